// Round 7
// baseline (511.957 us; speedup 1.0000x reference)
//
#include <hip/hip_runtime.h>

typedef __attribute__((ext_vector_type(8))) short v8s;
typedef __attribute__((ext_vector_type(8))) unsigned short v8u;
typedef __attribute__((ext_vector_type(4))) unsigned short v4u;
typedef __attribute__((ext_vector_type(4))) float f32x4;
typedef __attribute__((ext_vector_type(16))) float f32x16;

#define DEV __device__ __forceinline__

DEV unsigned short f2bf(float f) {
  union { float f; unsigned u; } v; v.f = f;
  unsigned r = v.u + 0x7fffu + ((v.u >> 16) & 1u);
  return (unsigned short)(r >> 16);
}

DEV void gload16(const unsigned short* g, unsigned short* l) {
  __builtin_amdgcn_global_load_lds(
      (const __attribute__((address_space(1))) unsigned int*)g,
      (__attribute__((address_space(3))) unsigned int*)l, 16, 0, 0);
}

#define SL2E 0.1803368801111204f  // 0.125 * log2(e)

// ------------------------------------------------------------------
// LayerNorm -> bf16
// ------------------------------------------------------------------
__global__ __launch_bounds__(256) void ln_kernel(
    const float* __restrict__ x, unsigned short* __restrict__ h,
    const float* __restrict__ alpha, const float* __restrict__ beta)
{
  int row = blockIdx.x;
  int tid = threadIdx.x;
  const float4* xr = reinterpret_cast<const float4*>(x + (size_t)row * 1024);
  float4 v = xr[tid];
  float s  = v.x + v.y + v.z + v.w;
  float ss = v.x * v.x + v.y * v.y + v.z * v.z + v.w * v.w;
#pragma unroll
  for (int off = 1; off < 64; off <<= 1) {
    s  += __shfl_xor(s, off);
    ss += __shfl_xor(ss, off);
  }
  __shared__ float ps[4][2];
  int wid = tid >> 6, lane = tid & 63;
  if (lane == 0) { ps[wid][0] = s; ps[wid][1] = ss; }
  __syncthreads();
  s  = ps[0][0] + ps[1][0] + ps[2][0] + ps[3][0];
  ss = ps[0][1] + ps[1][1] + ps[2][1] + ps[3][1];
  float mean = s * (1.0f / 1024.0f);
  float var  = (ss - 1024.0f * mean * mean) * (1.0f / 1023.0f);
  float inv  = 1.0f / (sqrtf(fmaxf(var, 0.0f)) + 1e-6f);
  float a = alpha[0], b = beta[0];
  v4u o;
  o[0] = f2bf(a * ((v.x - mean) * inv) + b);
  o[1] = f2bf(a * ((v.y - mean) * inv) + b);
  o[2] = f2bf(a * ((v.z - mean) * inv) + b);
  o[3] = f2bf(a * ((v.w - mean) * inv) + b);
  *reinterpret_cast<v4u*>(h + (size_t)row * 1024 + tid * 4) = o;
}

// ------------------------------------------------------------------
// fp32 W[K][N] -> bf16 Wt[N][K]
// ------------------------------------------------------------------
__global__ __launch_bounds__(256) void transpose_convert(
    const float* __restrict__ W, unsigned short* __restrict__ Wt, int K, int N)
{
  __shared__ float t[32][33];
  int n0 = blockIdx.x * 32, k0 = blockIdx.y * 32;
  int tx = threadIdx.x, ty = threadIdx.y;
#pragma unroll
  for (int i = 0; i < 4; ++i)
    t[ty + i * 8][tx] = W[(size_t)(k0 + ty + i * 8) * N + n0 + tx];
  __syncthreads();
#pragma unroll
  for (int i = 0; i < 4; ++i)
    Wt[(size_t)(n0 + ty + i * 8) * K + k0 + tx] = f2bf(t[tx][ty + i * 8]);
}

// ------------------------------------------------------------------
// Pipelined bf16 GEMM: tile 128x256, BK=64, 8 waves (2M x 4N),
// 3 LDS K-tile buffers, counted vmcnt(6), 32x32x16 MFMA,
// row-major XOR-swizzled LDS via pre-swizzled global source.
// ------------------------------------------------------------------
enum { MODE_QKV = 0, MODE_RES = 2, MODE_FFN1 = 3 };

#define BUF_ELEMS ((128 + 256) * 64)

DEV void stage_part(const unsigned short* Aptr, const unsigned short* Bptr,
                    unsigned short* buf, int K, int part, int wid, int lane)
{
  // part 0: A slab 0, B slabs 0,1 ; part 1: A slab 1, B slabs 2,3
  {
    int d = (part * 8 + wid) * 64 + lane;      // A granule 0..1023
    int r = d >> 3, p = d & 7;
    gload16(Aptr + (size_t)r * K + 8 * (p ^ (r & 7)),
            buf + (size_t)(part * 8 + wid) * 512);
  }
#pragma unroll
  for (int j = 0; j < 2; ++j) {
    int ib = part * 2 + j;
    int d = (ib * 8 + wid) * 64 + lane;        // B granule 0..2047
    int r = d >> 3, p = d & 7;
    gload16(Bptr + (size_t)r * K + 8 * (p ^ (r & 7)),
            buf + 128 * 64 + (size_t)(ib * 8 + wid) * 512);
  }
}

template <int MODE>
__global__ __launch_bounds__(512, 2) void gemm_pipe(
    const unsigned short* __restrict__ A, const unsigned short* __restrict__ Bt,
    const float* __restrict__ bias0, const float* __restrict__ bias1,
    const float* __restrict__ bias2, const float* __restrict__ resid,
    void* __restrict__ o0, void* __restrict__ o1, void* __restrict__ o2,
    int M, int N, int K)
{
  __shared__ unsigned short lds[3 * BUF_ELEMS];

  int nbx = M >> 7, nwg = gridDim.x;
  int lin = blockIdx.x;
  int qq = nwg >> 3, rr = nwg & 7;
  int xcd = lin & 7, idx = lin >> 3;
  int swz = (xcd < rr ? xcd * (qq + 1) : rr * (qq + 1) + (xcd - rr) * qq) + idx;
  int bx = swz % nbx, by = swz / nbx;

  int tid = threadIdx.x, lane = tid & 63, wid = tid >> 6;
  int wm = wid >> 2, wn = wid & 3;
  int l31 = lane & 31, g2 = lane >> 5;
  int rowBase = bx * 128, colBase = by * 256;

  const unsigned short* Ab = A  + (size_t)rowBase * K;
  const unsigned short* Bb = Bt + (size_t)colBase * K;
  int NT = K >> 6;

  f32x16 acc[2][2];
#pragma unroll
  for (int m = 0; m < 2; ++m)
#pragma unroll
    for (int n = 0; n < 2; ++n)
#pragma unroll
      for (int e = 0; e < 16; ++e) acc[m][n][e] = 0.f;

  // prologue: stage tiles 0 and 1
  stage_part(Ab, Bb, lds, K, 0, wid, lane);
  stage_part(Ab, Bb, lds, K, 1, wid, lane);
  stage_part(Ab + 64, Bb + 64, lds + BUF_ELEMS, K, 0, wid, lane);
  stage_part(Ab + 64, Bb + 64, lds + BUF_ELEMS, K, 1, wid, lane);
  asm volatile("s_waitcnt vmcnt(6)" ::: "memory");
  __builtin_amdgcn_s_barrier();
  asm volatile("" ::: "memory");

  int cur = 0;
  for (int t = 0; t < NT; ++t) {
    const char* Abuf = (const char*)(lds + cur * BUF_ELEMS);
    const char* Bbuf = Abuf + 128 * 128;
    int nxt2 = cur + 2; if (nxt2 >= 3) nxt2 -= 3;
    unsigned short* sbuf = lds + nxt2 * BUF_ELEMS;
    bool doStage = (t + 2 < NT);
    int ks_ = (t + 2) << 6;

#pragma unroll
    for (int ph = 0; ph < 2; ++ph) {           // K-half of 32 = 2 k-steps of 16
      v8s af[2][2], bfr[2][2];
#pragma unroll
      for (int mf = 0; mf < 2; ++mf)
#pragma unroll
        for (int ks = 0; ks < 2; ++ks) {
          int row = wm * 64 + mf * 32 + l31;
          int u = ph * 4 + ks * 2 + g2;
          af[mf][ks] = *reinterpret_cast<const v8s*>(
              Abuf + row * 128 + ((u * 16) ^ ((row & 7) << 4)));
        }
#pragma unroll
      for (int nf = 0; nf < 2; ++nf)
#pragma unroll
        for (int ks = 0; ks < 2; ++ks) {
          int row = wn * 64 + nf * 32 + l31;
          int u = ph * 4 + ks * 2 + g2;
          bfr[nf][ks] = *reinterpret_cast<const v8s*>(
              Bbuf + row * 128 + ((u * 16) ^ ((row & 7) << 4)));
        }

      if (doStage) stage_part(Ab + ks_, Bb + ks_, sbuf, K, ph, wid, lane);

      __builtin_amdgcn_s_setprio(1);
#pragma unroll
      for (int ks = 0; ks < 2; ++ks)
#pragma unroll
        for (int mf = 0; mf < 2; ++mf)
#pragma unroll
          for (int nf = 0; nf < 2; ++nf)
            acc[mf][nf] = __builtin_amdgcn_mfma_f32_32x32x16_bf16(
                af[mf][ks], bfr[nf][ks], acc[mf][nf], 0, 0, 0);
      __builtin_amdgcn_s_setprio(0);

      if (ph == 1) {
        if (doStage) asm volatile("s_waitcnt vmcnt(6)" ::: "memory");
        else         asm volatile("s_waitcnt vmcnt(0)" ::: "memory");
      }
      __builtin_amdgcn_sched_barrier(0);
      __builtin_amdgcn_s_barrier();
      asm volatile("" ::: "memory");
    }
    cur = cur + 1; if (cur >= 3) cur -= 3;
  }

  // ---- epilogue: C/D 32x32 layout: col=lane&31, row=(reg&3)+8*(reg>>2)+4*(lane>>5)
#pragma unroll
  for (int mf = 0; mf < 2; ++mf) {
#pragma unroll
    for (int nf = 0; nf < 2; ++nf) {
#pragma unroll
      for (int qg = 0; qg < 4; ++qg) {
#pragma unroll
        for (int j = 0; j < 4; ++j) {
          int row = rowBase + wm * 64 + mf * 32 + qg * 8 + g2 * 4 + j;
          int col = colBase + wn * 64 + nf * 32 + l31;
          float v = acc[mf][nf][qg * 4 + j];
          if constexpr (MODE == MODE_QKV) {
            int sect = colBase >> 10;            // block-uniform
            int cs = col & 1023;
            const float* bp = sect == 0 ? bias0 : (sect == 1 ? bias1 : bias2);
            v += bp[cs];
            int hh = cs >> 6, d = cs & 63;
            int b = row >> 11, sI = row & 2047;
            size_t bh = (size_t)(b * 16 + hh);
            if (sect == 0) {
              ((unsigned short*)o0)[(bh * 2048 + sI) * 64 + d] = f2bf(v * SL2E);
            } else if (sect == 1) {
              ((unsigned short*)o1)[(bh * 2048 + sI) * 64 + d] = f2bf(v);
            } else {
              int k6 = sI & 63;
              int slot = ((k6 >> 5) << 5) | (((k6 >> 2) & 3) << 3) |
                         (((k6 >> 4) & 1) << 2) | (k6 & 3);
              int e = slot ^ ((d & 7) << 3);
              ((unsigned short*)o2)[((bh * 32 + (sI >> 6)) * 64 + d) * 64 + e] = f2bf(v);
            }
          } else if constexpr (MODE == MODE_RES) {
            v += bias0[col];
            ((float*)o0)[(size_t)row * N + col] = resid[(size_t)row * N + col] + v;
          } else { // MODE_FFN1
            v += bias0[col];
            ((unsigned short*)o0)[(size_t)row * N + col] = f2bf(fmaxf(v, 0.0f));
          }
        }
      }
    }
  }
}

// ------------------------------------------------------------------
// Flash attention v5: QBLK=128 (2 q-sets/wave), swapped QK^T,
// double-buffered LDS, K + pre-permuted V via global_load_lds,
// K/V fragments reused across both q-sets, defer-max softmax.
// ------------------------------------------------------------------
__global__ __launch_bounds__(256) void attn_kernel(
    const unsigned short* __restrict__ q, const unsigned short* __restrict__ k,
    const unsigned short* __restrict__ vP, const int* __restrict__ mask,
    unsigned short* __restrict__ ctx)
{
  const int S = 2048, DK = 64, NT = 32;
  int bh = blockIdx.x;
  int b = bh >> 4, hh = bh & 15;
  int qbase = blockIdx.y * 128;
  int tid = threadIdx.x, lane = tid & 63, wid = tid >> 6;
  int g = lane >> 4, c0 = lane & 15;

  __shared__ unsigned short Ks[2][4096];
  __shared__ unsigned short Vs[2][4096];

  const unsigned short* qb  = q  + (size_t)bh * S * DK;
  const unsigned short* kb  = k  + (size_t)bh * S * DK;
  const unsigned short* vPb = vP + (size_t)bh * 32 * 4096;
  const int* mb = mask + b * S;

  int qrow = qbase + wid * 32 + c0;
  v8s aq[2][2];
#pragma unroll
  for (int s = 0; s < 2; ++s)
#pragma unroll
    for (int t = 0; t < 2; ++t)
      aq[s][t] = *reinterpret_cast<const v8s*>(
          &qb[(size_t)(qrow + s * 16) * DK + t * 32 + g * 8]);

  int i0 = tid, i1 = tid + 256;
  int r0 = i0 >> 3, m0 = i0 & 7;
  int r1 = i1 >> 3, m1 = i1 & 7;
  const unsigned short* ks0 = kb + (size_t)r0 * DK + 8 * (m0 ^ (r0 & 7));
  const unsigned short* ks1 = kb + (size_t)r1 * DK + 8 * (m1 ^ (r1 & 7));

  f32x4 acc[2][4];
#pragma unroll
  for (int s = 0; s < 2; ++s)
#pragma unroll
    for (int no = 0; no < 4; ++no) acc[s][no] = (f32x4){0.f, 0.f, 0.f, 0.f};
  float mrow[2] = {-1e30f, -1e30f}, lrow[2] = {0.f, 0.f};

  // prologue: stage tile 0
  gload16(ks0, &Ks[0][i0 * 8]);
  gload16(ks1, &Ks[0][i1 * 8]);
  gload16(vPb + i0 * 8, &Vs[0][i0 * 8]);
  gload16(vPb + i1 * 8, &Vs[0][i1 * 8]);
  __syncthreads();

  for (int t = 0; t < NT; ++t) {
    int cur = t & 1, nxt = cur ^ 1;
    if (t + 1 < NT) {
      int kofs = (t + 1) * 64 * DK;
      gload16(ks0 + kofs, &Ks[nxt][i0 * 8]);
      gload16(ks1 + kofs, &Ks[nxt][i1 * 8]);
      gload16(vPb + (t + 1) * 4096 + i0 * 8, &Vs[nxt][i0 * 8]);
      gload16(vPb + (t + 1) * 4096 + i1 * 8, &Vs[nxt][i1 * 8]);
    }
    int mv = mb[t * 64 + lane];
    bool allv = __all(mv != 0);

    // ---- QK^T for both q-sets (K frags read once) ----
    float p0[16], p1[16];
#pragma unroll
    for (int n = 0; n < 4; ++n) {
      int kvr = n * 16 + c0;
      const char* krow = (const char*)&Ks[cur][kvr * DK];
      int sw = (kvr & 7) << 4;
      v8s ak0 = *reinterpret_cast<const v8s*>(krow + ((g * 16) ^ sw));
      v8s ak1 = *reinterpret_cast<const v8s*>(krow + ((64 + g * 16) ^ sw));
      f32x4 s0 = (f32x4){0.f, 0.f, 0.f, 0.f};
      f32x4 s1 = (f32x4){0.f, 0.f, 0.f, 0.f};
      s0 = __builtin_amdgcn_mfma_f32_16x16x32_bf16(ak0, aq[0][0], s0, 0, 0, 0);
      s0 = __builtin_amdgcn_mfma_f32_16x16x32_bf16(ak1, aq[0][1], s0, 0, 0, 0);
      s1 = __builtin_amdgcn_mfma_f32_16x16x32_bf16(ak0, aq[1][0], s1, 0, 0, 0);
      s1 = __builtin_amdgcn_mfma_f32_16x16x32_bf16(ak1, aq[1][1], s1, 0, 0, 0);
#pragma unroll
      for (int r = 0; r < 4; ++r) { p0[n * 4 + r] = s0[r]; p1[n * 4 + r] = s1[r]; }
    }
    if (!allv) {
#pragma unroll
      for (int n = 0; n < 4; ++n) {
        int4 mm = *reinterpret_cast<const int4*>(&mb[t * 64 + n * 16 + g * 4]);
        float a0 = mm.x ? 0.f : -1e9f, a1 = mm.y ? 0.f : -1e9f;
        float a2 = mm.z ? 0.f : -1e9f, a3 = mm.w ? 0.f : -1e9f;
        p0[n * 4 + 0] += a0; p1[n * 4 + 0] += a0;
        p0[n * 4 + 1] += a1; p1[n * 4 + 1] += a1;
        p0[n * 4 + 2] += a2; p1[n * 4 + 2] += a2;
        p0[n * 4 + 3] += a3; p1[n * 4 + 3] += a3;
      }
    }

    // ---- online softmax both sets (defer-max, THR=8, log2 domain) ----
    float pm0 = p0[0], pm1 = p1[0];
#pragma unroll
    for (int i = 1; i < 16; ++i) { pm0 = fmaxf(pm0, p0[i]); pm1 = fmaxf(pm1, p1[i]); }
    pm0 = fmaxf(pm0, __shfl_xor(pm0, 16)); pm0 = fmaxf(pm0, __shfl_xor(pm0, 32));
    pm1 = fmaxf(pm1, __shfl_xor(pm1, 16)); pm1 = fmaxf(pm1, __shfl_xor(pm1, 32));
    bool ok = (pm0 - mrow[0] <= 8.0f) && (pm1 - mrow[1] <= 8.0f);
    if (!__all(ok)) {
      float mn0 = fmaxf(mrow[0], pm0), mn1 = fmaxf(mrow[1], pm1);
      float sc0 = exp2f(mrow[0] - mn0), sc1 = exp2f(mrow[1] - mn1);
      lrow[0] *= sc0; lrow[1] *= sc1;
#pragma unroll
      for (int no = 0; no < 4; ++no) {
#pragma unroll
        for (int r = 0; r < 4; ++r) { acc[0][no][r] *= sc0; acc[1][no][r] *= sc1; }
      }
      mrow[0] = mn0; mrow[1] = mn1;
    }
    float ts0 = 0.f, ts1 = 0.f;
#pragma unroll
    for (int i = 0; i < 16; ++i) {
      p0[i] = exp2f(p0[i] - mrow[0]); ts0 += p0[i];
      p1[i] = exp2f(p1[i] - mrow[1]); ts1 += p1[i];
    }
    ts0 += __shfl_xor(ts0, 16); ts0 += __shfl_xor(ts0, 32);
    ts1 += __shfl_xor(ts1, 16); ts1 += __shfl_xor(ts1, 32);
    lrow[0] += ts0; lrow[1] += ts1;

    // ---- pack P to bf16 ----
    v8s pb0[2], pb1[2];
#pragma unroll
    for (int c = 0; c < 2; ++c) {
      union { v8s s; unsigned u[4]; } k0, k1;
#pragma unroll
      for (int hp = 0; hp < 4; ++hp) {
        asm("v_cvt_pk_bf16_f32 %0, %1, %2"
            : "=v"(k0.u[hp]) : "v"(p0[c * 8 + 2 * hp]), "v"(p0[c * 8 + 2 * hp + 1]));
        asm("v_cvt_pk_bf16_f32 %0, %1, %2"
            : "=v"(k1.u[hp]) : "v"(p1[c * 8 + 2 * hp]), "v"(p1[c * 8 + 2 * hp + 1]));
      }
      pb0[c] = k0.s; pb1[c] = k1.s;
    }

    // ---- PV: V frags read once, used by both q-sets ----
#pragma unroll
    for (int c = 0; c < 2; ++c) {
#pragma unroll
      for (int no = 0; no < 4; ++no) {
        int d = no * 16 + c0;
        v8s av = *reinterpret_cast<const v8s*>(
            (const char*)&Vs[cur][d * 64] + ((c * 64 + g * 16) ^ ((d & 7) << 4)));
        acc[0][no] = __builtin_amdgcn_mfma_f32_16x16x32_bf16(av, pb0[c], acc[0][no], 0, 0, 0);
        acc[1][no] = __builtin_amdgcn_mfma_f32_16x16x32_bf16(av, pb1[c], acc[1][no], 0, 0, 0);
      }
    }
    __syncthreads();
  }

#pragma unroll
  for (int s = 0; s < 2; ++s) {
    float inv = 1.0f / fmaxf(lrow[s], 1e-20f);
#pragma unroll
    for (int no = 0; no < 4; ++no) {
      v4u o;
      o[0] = f2bf(acc[s][no][0] * inv);
      o[1] = f2bf(acc[s][no][1] * inv);
      o[2] = f2bf(acc[s][no][2] * inv);
      o[3] = f2bf(acc[s][no][3] * inv);
      *reinterpret_cast<v4u*>(
          &ctx[(size_t)(b * S + qrow + s * 16) * 1024 + hh * 64 + no * 16 + g * 4]) = o;
    }
  }
}

// ------------------------------------------------------------------
extern "C" void kernel_launch(void* const* d_in, const int* in_sizes, int n_in,
                              void* d_out, int out_size, void* d_ws, size_t ws_size,
                              hipStream_t stream)
{
  (void)in_sizes; (void)n_in; (void)out_size; (void)ws_size;
  const float* x    = (const float*)d_in[0];
  const int*   mask = (const int*)d_in[1];
  const float* Wq = (const float*)d_in[2];  const float* bq = (const float*)d_in[3];
  const float* Wk = (const float*)d_in[4];  const float* bk = (const float*)d_in[5];
  const float* Wv = (const float*)d_in[6];  const float* bv = (const float*)d_in[7];
  const float* Wo = (const float*)d_in[8];  const float* bo = (const float*)d_in[9];
  const float* W1 = (const float*)d_in[10]; const float* b1 = (const float*)d_in[11];
  const float* W2 = (const float*)d_in[12]; const float* b2 = (const float*)d_in[13];
  const float* ln1a = (const float*)d_in[14]; const float* ln1b = (const float*)d_in[15];
  const float* ln2a = (const float*)d_in[16]; const float* ln2b = (const float*)d_in[17];

  char* ws = (char*)d_ws;
  const size_t MB = (size_t)1 << 20;
  unsigned short* wqkvT = (unsigned short*)(ws + 0 * MB);  // [3072][1024]
  unsigned short* woT = (unsigned short*)(ws + 6 * MB);    // [1024][1024]
  unsigned short* w1T = (unsigned short*)(ws + 8 * MB);    // [4096][1024]
  unsigned short* w2T = (unsigned short*)(ws + 16 * MB);   // [1024][4096]
  unsigned short* hb  = (unsigned short*)(ws + 24 * MB);   // LN out, 8192x1024
  unsigned short* qb  = (unsigned short*)(ws + 40 * MB);   // [bh][S][64], pre-scaled
  unsigned short* kb  = (unsigned short*)(ws + 56 * MB);   // [bh][S][64]
  unsigned short* vPb = (unsigned short*)(ws + 72 * MB);   // [bh][32][64][64] permuted
  unsigned short* ctx = (unsigned short*)(ws + 88 * MB);   // 8192x1024
  unsigned short* gb  = (unsigned short*)(ws + 40 * MB);   // FFN mid (aliases dead bufs)
  float* xout = (float*)d_out;

  dim3 tb(32, 8);
  transpose_convert<<<dim3(32, 32),  tb, 0, stream>>>(Wq, wqkvT,               1024, 1024);
  transpose_convert<<<dim3(32, 32),  tb, 0, stream>>>(Wk, wqkvT + 1024 * 1024, 1024, 1024);
  transpose_convert<<<dim3(32, 32),  tb, 0, stream>>>(Wv, wqkvT + 2048 * 1024, 1024, 1024);
  transpose_convert<<<dim3(32, 32),  tb, 0, stream>>>(Wo, woT, 1024, 1024);
  transpose_convert<<<dim3(128, 32), tb, 0, stream>>>(W1, w1T, 1024, 4096);
  transpose_convert<<<dim3(32, 128), tb, 0, stream>>>(W2, w2T, 4096, 1024);

  ln_kernel<<<8192, 256, 0, stream>>>(x, hb, ln1a, ln1b);

  // QKV merged: M=8192, N=3072, K=1024 -> 64 x 12 = 768 WGs
  gemm_pipe<MODE_QKV><<<768, 512, 0, stream>>>(
      hb, wqkvT, bq, bk, bv, nullptr, qb, kb, vPb, 8192, 3072, 1024);

  attn_kernel<<<dim3(64, 16), 256, 0, stream>>>(qb, kb, vPb, mask, ctx);

  // WO: M=8192, N=1024, K=1024 -> 64 x 4 = 256 WGs
  gemm_pipe<MODE_RES><<<256, 512, 0, stream>>>(
      ctx, woT, bo, nullptr, nullptr, x, xout, nullptr, nullptr, 8192, 1024, 1024);

  ln_kernel<<<8192, 256, 0, stream>>>(xout, hb, ln2a, ln2b);

  // FFN1: M=8192, N=4096, K=1024 -> 64 x 16 = 1024 WGs
  gemm_pipe<MODE_FFN1><<<1024, 512, 0, stream>>>(
      hb, w1T, b1, nullptr, nullptr, nullptr, gb, nullptr, nullptr, 8192, 4096, 1024);

  // FFN2: M=8192, N=1024, K=4096 -> 64 x 4 = 256 WGs
  gemm_pipe<MODE_RES><<<256, 512, 0, stream>>>(
      gb, w2T, b2, nullptr, nullptr, xout, xout, nullptr, nullptr, 8192, 1024, 4096);
}

// Round 8
// 449.489 us; speedup vs baseline: 1.1390x; 1.1390x over previous
//
#include <hip/hip_runtime.h>

typedef __attribute__((ext_vector_type(8))) short v8s;
typedef __attribute__((ext_vector_type(8))) unsigned short v8u;
typedef __attribute__((ext_vector_type(4))) unsigned short v4u;
typedef __attribute__((ext_vector_type(4))) float f32x4;

#define DEV __device__ __forceinline__

DEV unsigned short f2bf(float f) {
  union { float f; unsigned u; } v; v.f = f;
  unsigned r = v.u + 0x7fffu + ((v.u >> 16) & 1u);
  return (unsigned short)(r >> 16);
}

DEV void gload16(const unsigned short* g, unsigned short* l) {
  __builtin_amdgcn_global_load_lds(
      (const __attribute__((address_space(1))) unsigned int*)g,
      (__attribute__((address_space(3))) unsigned int*)l, 16, 0, 0);
}

#define SL2E 0.1803368801111204f  // 0.125 * log2(e)

// ------------------------------------------------------------------
// LayerNorm -> bf16
// ------------------------------------------------------------------
__global__ __launch_bounds__(256) void ln_kernel(
    const float* __restrict__ x, unsigned short* __restrict__ h,
    const float* __restrict__ alpha, const float* __restrict__ beta)
{
  int row = blockIdx.x;
  int tid = threadIdx.x;
  const float4* xr = reinterpret_cast<const float4*>(x + (size_t)row * 1024);
  float4 v = xr[tid];
  float s  = v.x + v.y + v.z + v.w;
  float ss = v.x * v.x + v.y * v.y + v.z * v.z + v.w * v.w;
#pragma unroll
  for (int off = 1; off < 64; off <<= 1) {
    s  += __shfl_xor(s, off);
    ss += __shfl_xor(ss, off);
  }
  __shared__ float ps[4][2];
  int wid = tid >> 6, lane = tid & 63;
  if (lane == 0) { ps[wid][0] = s; ps[wid][1] = ss; }
  __syncthreads();
  s  = ps[0][0] + ps[1][0] + ps[2][0] + ps[3][0];
  ss = ps[0][1] + ps[1][1] + ps[2][1] + ps[3][1];
  float mean = s * (1.0f / 1024.0f);
  float var  = (ss - 1024.0f * mean * mean) * (1.0f / 1023.0f);
  float inv  = 1.0f / (sqrtf(fmaxf(var, 0.0f)) + 1e-6f);
  float a = alpha[0], b = beta[0];
  v4u o;
  o[0] = f2bf(a * ((v.x - mean) * inv) + b);
  o[1] = f2bf(a * ((v.y - mean) * inv) + b);
  o[2] = f2bf(a * ((v.z - mean) * inv) + b);
  o[3] = f2bf(a * ((v.w - mean) * inv) + b);
  *reinterpret_cast<v4u*>(h + (size_t)row * 1024 + tid * 4) = o;
}

// ------------------------------------------------------------------
// fp32 W[K][N] -> bf16 Wt[N][K]
// ------------------------------------------------------------------
__global__ __launch_bounds__(256) void transpose_convert(
    const float* __restrict__ W, unsigned short* __restrict__ Wt, int K, int N)
{
  __shared__ float t[32][33];
  int n0 = blockIdx.x * 32, k0 = blockIdx.y * 32;
  int tx = threadIdx.x, ty = threadIdx.y;
#pragma unroll
  for (int i = 0; i < 4; ++i)
    t[ty + i * 8][tx] = W[(size_t)(k0 + ty + i * 8) * N + n0 + tx];
  __syncthreads();
#pragma unroll
  for (int i = 0; i < 4; ++i)
    Wt[(size_t)(n0 + ty + i * 8) * K + k0 + tx] = f2bf(t[tx][ty + i * 8]);
}

// ------------------------------------------------------------------
// Pipelined bf16 GEMM (round-5 verified structure): tile 128x256,
// BK=64, 8 waves (2M x 4N), 3 LDS K-tile buffers, counted vmcnt(6),
// 16x16x32 MFMA, row-major XOR-swizzled LDS via pre-swizzled source.
// ------------------------------------------------------------------
enum { MODE_QKV = 0, MODE_RES = 2, MODE_FFN1 = 3 };

#define BUF_ELEMS ((128 + 256) * 64)

DEV void stage_part(const unsigned short* Aptr, const unsigned short* Bptr,
                    unsigned short* buf, int K, int part, int wid, int lane)
{
  {
    int d = (part * 8 + wid) * 64 + lane;      // A granule 0..1023
    int r = d >> 3, p = d & 7;
    gload16(Aptr + (size_t)r * K + 8 * (p ^ (r & 7)),
            buf + (size_t)(part * 8 + wid) * 512);
  }
#pragma unroll
  for (int j = 0; j < 2; ++j) {
    int ib = part * 2 + j;
    int d = (ib * 8 + wid) * 64 + lane;        // B granule 0..2047
    int r = d >> 3, p = d & 7;
    gload16(Bptr + (size_t)r * K + 8 * (p ^ (r & 7)),
            buf + 128 * 64 + (size_t)(ib * 8 + wid) * 512);
  }
}

template <int MODE>
__global__ __launch_bounds__(512, 2) void gemm_pipe(
    const unsigned short* __restrict__ A, const unsigned short* __restrict__ Bt,
    const float* __restrict__ bias0, const float* __restrict__ bias1,
    const float* __restrict__ bias2, const float* __restrict__ resid,
    void* __restrict__ o0, void* __restrict__ o1, void* __restrict__ o2,
    int M, int N, int K)
{
  __shared__ unsigned short lds[3 * BUF_ELEMS];

  int nbx = M >> 7, nwg = gridDim.x;
  int lin = blockIdx.x;
  int qq = nwg >> 3, rr = nwg & 7;
  int xcd = lin & 7, idx = lin >> 3;
  int swz = (xcd < rr ? xcd * (qq + 1) : rr * (qq + 1) + (xcd - rr) * qq) + idx;
  int bx = swz % nbx, by = swz / nbx;

  int tid = threadIdx.x, lane = tid & 63, wid = tid >> 6;
  int wm = wid >> 2, wn = wid & 3;
  int g = lane >> 4, c0 = lane & 15;
  int rowBase = bx * 128, colBase = by * 256;

  const unsigned short* Ab = A  + (size_t)rowBase * K;
  const unsigned short* Bb = Bt + (size_t)colBase * K;
  int NT = K >> 6;

  f32x4 acc[4][4];
#pragma unroll
  for (int m = 0; m < 4; ++m)
#pragma unroll
    for (int n = 0; n < 4; ++n) acc[m][n] = (f32x4){0.f, 0.f, 0.f, 0.f};

  // prologue: stage tiles 0 and 1
  stage_part(Ab, Bb, lds, K, 0, wid, lane);
  stage_part(Ab, Bb, lds, K, 1, wid, lane);
  stage_part(Ab + 64, Bb + 64, lds + BUF_ELEMS, K, 0, wid, lane);
  stage_part(Ab + 64, Bb + 64, lds + BUF_ELEMS, K, 1, wid, lane);
  asm volatile("s_waitcnt vmcnt(6)" ::: "memory");
  __builtin_amdgcn_s_barrier();
  asm volatile("" ::: "memory");

  int cur = 0;
  for (int t = 0; t < NT; ++t) {
    const char* Abuf = (const char*)(lds + cur * BUF_ELEMS);
    const char* Bbuf = Abuf + 128 * 128;
    int nxt2 = cur + 2; if (nxt2 >= 3) nxt2 -= 3;
    unsigned short* sbuf = lds + nxt2 * BUF_ELEMS;
    bool doStage = (t + 2 < NT);
    int ks_ = (t + 2) << 6;
    int e = (c0 & 7) << 4;

#pragma unroll
    for (int ph = 0; ph < 2; ++ph) {           // ph = K-half: frags read ONCE
      v8s af[4], bfr[4];
#pragma unroll
      for (int m = 0; m < 4; ++m)
        af[m] = *reinterpret_cast<const v8s*>(
            Abuf + (wm * 64 + m * 16 + c0) * 128 + ((ph * 64 + g * 16) ^ e));
#pragma unroll
      for (int n = 0; n < 4; ++n)
        bfr[n] = *reinterpret_cast<const v8s*>(
            Bbuf + (wn * 64 + n * 16 + c0) * 128 + ((ph * 64 + g * 16) ^ e));

      if (doStage) stage_part(Ab + ks_, Bb + ks_, sbuf, K, ph, wid, lane);

      __builtin_amdgcn_s_setprio(1);
#pragma unroll
      for (int m = 0; m < 4; ++m)
#pragma unroll
        for (int n = 0; n < 4; ++n)
          acc[m][n] = __builtin_amdgcn_mfma_f32_16x16x32_bf16(
              af[m], bfr[n], acc[m][n], 0, 0, 0);
      __builtin_amdgcn_s_setprio(0);

      if (ph == 1) {
        if (doStage) asm volatile("s_waitcnt vmcnt(6)" ::: "memory");
        else         asm volatile("s_waitcnt vmcnt(0)" ::: "memory");
      }
      __builtin_amdgcn_sched_barrier(0);
      __builtin_amdgcn_s_barrier();
      asm volatile("" ::: "memory");
    }
    cur = cur + 1; if (cur >= 3) cur -= 3;
  }

  // ---- epilogue (16x16 C/D: col=lane&15, row=(lane>>4)*4+reg) ----
#pragma unroll
  for (int mf = 0; mf < 4; ++mf) {
#pragma unroll
    for (int nf = 0; nf < 4; ++nf) {
#pragma unroll
      for (int r = 0; r < 4; ++r) {
        int row = rowBase + wm * 64 + mf * 16 + g * 4 + r;
        int col = colBase + wn * 64 + nf * 16 + c0;
        float v = acc[mf][nf][r];
        if constexpr (MODE == MODE_QKV) {
          int sect = colBase >> 10;              // block-uniform
          int cs = col & 1023;
          const float* bp = sect == 0 ? bias0 : (sect == 1 ? bias1 : bias2);
          v += bp[cs];
          int hh = cs >> 6, d = cs & 63;
          int b = row >> 11, sI = row & 2047;
          size_t bh = (size_t)(b * 16 + hh);
          if (sect == 0) {
            ((unsigned short*)o0)[(bh * 2048 + sI) * 64 + d] = f2bf(v * SL2E);
          } else if (sect == 1) {
            ((unsigned short*)o1)[(bh * 2048 + sI) * 64 + d] = f2bf(v);
          } else {
            int k6 = sI & 63;
            int slot = ((k6 >> 5) << 5) | (((k6 >> 2) & 3) << 3) |
                       (((k6 >> 4) & 1) << 2) | (k6 & 3);
            int e2 = slot ^ ((d & 7) << 3);
            ((unsigned short*)o2)[((bh * 32 + (sI >> 6)) * 64 + d) * 64 + e2] = f2bf(v);
          }
        } else if constexpr (MODE == MODE_RES) {
          v += bias0[col];
          ((float*)o0)[(size_t)row * N + col] = resid[(size_t)row * N + col] + v;
        } else { // MODE_FFN1
          v += bias0[col];
          ((unsigned short*)o0)[(size_t)row * N + col] = f2bf(fmaxf(v, 0.0f));
        }
      }
    }
  }
}

// ------------------------------------------------------------------
// Flash attention v6: QBLK=128 (2 q-sets/wave), swapped QK^T,
// double-buffered LDS, K + pre-permuted V via global_load_lds,
// FIXED-MAX softmax (p = exp2(s - 16), constant cancels in O=acc/l):
// no max reduce, no rescale, per-lane l-partials reduced once at end.
// ------------------------------------------------------------------
__global__ __launch_bounds__(256) void attn_kernel(
    const unsigned short* __restrict__ q, const unsigned short* __restrict__ k,
    const unsigned short* __restrict__ vP, const int* __restrict__ mask,
    unsigned short* __restrict__ ctx)
{
  const int S = 2048, DK = 64, NT = 32;
  const float M0 = 16.0f;
  int bh = blockIdx.x;
  int b = bh >> 4, hh = bh & 15;
  int qbase = blockIdx.y * 128;
  int tid = threadIdx.x, lane = tid & 63, wid = tid >> 6;
  int g = lane >> 4, c0 = lane & 15;

  __shared__ unsigned short Ks[2][4096];
  __shared__ unsigned short Vs[2][4096];

  const unsigned short* qb  = q  + (size_t)bh * S * DK;
  const unsigned short* kb  = k  + (size_t)bh * S * DK;
  const unsigned short* vPb = vP + (size_t)bh * 32 * 4096;
  const int* mb = mask + b * S;

  int qrow = qbase + wid * 32 + c0;
  v8s aq[2][2];
#pragma unroll
  for (int s = 0; s < 2; ++s)
#pragma unroll
    for (int t = 0; t < 2; ++t)
      aq[s][t] = *reinterpret_cast<const v8s*>(
          &qb[(size_t)(qrow + s * 16) * DK + t * 32 + g * 8]);

  int i0 = tid, i1 = tid + 256;
  int r0 = i0 >> 3, m0 = i0 & 7;
  int r1 = i1 >> 3, m1 = i1 & 7;
  const unsigned short* ks0 = kb + (size_t)r0 * DK + 8 * (m0 ^ (r0 & 7));
  const unsigned short* ks1 = kb + (size_t)r1 * DK + 8 * (m1 ^ (r1 & 7));

  f32x4 acc[2][4];
#pragma unroll
  for (int s = 0; s < 2; ++s)
#pragma unroll
    for (int no = 0; no < 4; ++no) acc[s][no] = (f32x4){0.f, 0.f, 0.f, 0.f};
  float lsum0 = 0.f, lsum1 = 0.f;

  // prologue: stage tile 0
  gload16(ks0, &Ks[0][i0 * 8]);
  gload16(ks1, &Ks[0][i1 * 8]);
  gload16(vPb + i0 * 8, &Vs[0][i0 * 8]);
  gload16(vPb + i1 * 8, &Vs[0][i1 * 8]);
  __syncthreads();

  for (int t = 0; t < NT; ++t) {
    int cur = t & 1, nxt = cur ^ 1;
    if (t + 1 < NT) {
      int kofs = (t + 1) * 64 * DK;
      gload16(ks0 + kofs, &Ks[nxt][i0 * 8]);
      gload16(ks1 + kofs, &Ks[nxt][i1 * 8]);
      gload16(vPb + (t + 1) * 4096 + i0 * 8, &Vs[nxt][i0 * 8]);
      gload16(vPb + (t + 1) * 4096 + i1 * 8, &Vs[nxt][i1 * 8]);
    }
    int mv = mb[t * 64 + lane];
    bool allv = __all(mv != 0);

    // ---- QK^T for both q-sets (K frags read once) ----
    float p0[16], p1[16];
#pragma unroll
    for (int n = 0; n < 4; ++n) {
      int kvr = n * 16 + c0;
      const char* krow = (const char*)&Ks[cur][kvr * DK];
      int sw = (kvr & 7) << 4;
      v8s ak0 = *reinterpret_cast<const v8s*>(krow + ((g * 16) ^ sw));
      v8s ak1 = *reinterpret_cast<const v8s*>(krow + ((64 + g * 16) ^ sw));
      f32x4 s0 = (f32x4){0.f, 0.f, 0.f, 0.f};
      f32x4 s1 = (f32x4){0.f, 0.f, 0.f, 0.f};
      s0 = __builtin_amdgcn_mfma_f32_16x16x32_bf16(ak0, aq[0][0], s0, 0, 0, 0);
      s0 = __builtin_amdgcn_mfma_f32_16x16x32_bf16(ak1, aq[0][1], s0, 0, 0, 0);
      s1 = __builtin_amdgcn_mfma_f32_16x16x32_bf16(ak0, aq[1][0], s1, 0, 0, 0);
      s1 = __builtin_amdgcn_mfma_f32_16x16x32_bf16(ak1, aq[1][1], s1, 0, 0, 0);
#pragma unroll
      for (int r = 0; r < 4; ++r) { p0[n * 4 + r] = s0[r]; p1[n * 4 + r] = s1[r]; }
    }
    if (!allv) {
#pragma unroll
      for (int n = 0; n < 4; ++n) {
        int4 mm = *reinterpret_cast<const int4*>(&mb[t * 64 + n * 16 + g * 4]);
        float a0 = mm.x ? 0.f : -1e9f, a1 = mm.y ? 0.f : -1e9f;
        float a2 = mm.z ? 0.f : -1e9f, a3 = mm.w ? 0.f : -1e9f;
        p0[n * 4 + 0] += a0; p1[n * 4 + 0] += a0;
        p0[n * 4 + 1] += a1; p1[n * 4 + 1] += a1;
        p0[n * 4 + 2] += a2; p1[n * 4 + 2] += a2;
        p0[n * 4 + 3] += a3; p1[n * 4 + 3] += a3;
      }
    }

    // ---- fixed-max softmax: p = exp2(s - M0); per-lane l partials ----
    float ts0 = 0.f, ts1 = 0.f;
#pragma unroll
    for (int i = 0; i < 16; ++i) {
      p0[i] = exp2f(p0[i] - M0); ts0 += p0[i];
      p1[i] = exp2f(p1[i] - M0); ts1 += p1[i];
    }
    lsum0 += ts0; lsum1 += ts1;

    // ---- pack P to bf16 ----
    v8s pb0[2], pb1[2];
#pragma unroll
    for (int c = 0; c < 2; ++c) {
      union { v8s s; unsigned u[4]; } k0, k1;
#pragma unroll
      for (int hp = 0; hp < 4; ++hp) {
        asm("v_cvt_pk_bf16_f32 %0, %1, %2"
            : "=v"(k0.u[hp]) : "v"(p0[c * 8 + 2 * hp]), "v"(p0[c * 8 + 2 * hp + 1]));
        asm("v_cvt_pk_bf16_f32 %0, %1, %2"
            : "=v"(k1.u[hp]) : "v"(p1[c * 8 + 2 * hp]), "v"(p1[c * 8 + 2 * hp + 1]));
      }
      pb0[c] = k0.s; pb1[c] = k1.s;
    }

    // ---- PV: V frags read once, used by both q-sets ----
#pragma unroll
    for (int c = 0; c < 2; ++c) {
#pragma unroll
      for (int no = 0; no < 4; ++no) {
        int d = no * 16 + c0;
        v8s av = *reinterpret_cast<const v8s*>(
            (const char*)&Vs[cur][d * 64] + ((c * 64 + g * 16) ^ ((d & 7) << 4)));
        acc[0][no] = __builtin_amdgcn_mfma_f32_16x16x32_bf16(av, pb0[c], acc[0][no], 0, 0, 0);
        acc[1][no] = __builtin_amdgcn_mfma_f32_16x16x32_bf16(av, pb1[c], acc[1][no], 0, 0, 0);
      }
    }
    __syncthreads();
  }

  // ---- one final l reduction across the 4 lane-groups ----
  lsum0 += __shfl_xor(lsum0, 16); lsum0 += __shfl_xor(lsum0, 32);
  lsum1 += __shfl_xor(lsum1, 16); lsum1 += __shfl_xor(lsum1, 32);
  float lrow[2] = {lsum0, lsum1};

#pragma unroll
  for (int s = 0; s < 2; ++s) {
    float inv = 1.0f / fmaxf(lrow[s], 1e-30f);
#pragma unroll
    for (int no = 0; no < 4; ++no) {
      v4u o;
      o[0] = f2bf(acc[s][no][0] * inv);
      o[1] = f2bf(acc[s][no][1] * inv);
      o[2] = f2bf(acc[s][no][2] * inv);
      o[3] = f2bf(acc[s][no][3] * inv);
      *reinterpret_cast<v4u*>(
          &ctx[(size_t)(b * S + qrow + s * 16) * 1024 + hh * 64 + no * 16 + g * 4]) = o;
    }
  }
}

// ------------------------------------------------------------------
extern "C" void kernel_launch(void* const* d_in, const int* in_sizes, int n_in,
                              void* d_out, int out_size, void* d_ws, size_t ws_size,
                              hipStream_t stream)
{
  (void)in_sizes; (void)n_in; (void)out_size; (void)ws_size;
  const float* x    = (const float*)d_in[0];
  const int*   mask = (const int*)d_in[1];
  const float* Wq = (const float*)d_in[2];  const float* bq = (const float*)d_in[3];
  const float* Wk = (const float*)d_in[4];  const float* bk = (const float*)d_in[5];
  const float* Wv = (const float*)d_in[6];  const float* bv = (const float*)d_in[7];
  const float* Wo = (const float*)d_in[8];  const float* bo = (const float*)d_in[9];
  const float* W1 = (const float*)d_in[10]; const float* b1 = (const float*)d_in[11];
  const float* W2 = (const float*)d_in[12]; const float* b2 = (const float*)d_in[13];
  const float* ln1a = (const float*)d_in[14]; const float* ln1b = (const float*)d_in[15];
  const float* ln2a = (const float*)d_in[16]; const float* ln2b = (const float*)d_in[17];

  char* ws = (char*)d_ws;
  const size_t MB = (size_t)1 << 20;
  unsigned short* wqkvT = (unsigned short*)(ws + 0 * MB);  // [3072][1024]
  unsigned short* woT = (unsigned short*)(ws + 6 * MB);    // [1024][1024]
  unsigned short* w1T = (unsigned short*)(ws + 8 * MB);    // [4096][1024]
  unsigned short* w2T = (unsigned short*)(ws + 16 * MB);   // [1024][4096]
  unsigned short* hb  = (unsigned short*)(ws + 24 * MB);   // LN out, 8192x1024
  unsigned short* qb  = (unsigned short*)(ws + 40 * MB);   // [bh][S][64], pre-scaled
  unsigned short* kb  = (unsigned short*)(ws + 56 * MB);   // [bh][S][64]
  unsigned short* vPb = (unsigned short*)(ws + 72 * MB);   // [bh][32][64][64] permuted
  unsigned short* ctx = (unsigned short*)(ws + 88 * MB);   // 8192x1024
  unsigned short* gb  = (unsigned short*)(ws + 40 * MB);   // FFN mid (aliases dead bufs)
  float* xout = (float*)d_out;

  dim3 tb(32, 8);
  transpose_convert<<<dim3(32, 32),  tb, 0, stream>>>(Wq, wqkvT,               1024, 1024);
  transpose_convert<<<dim3(32, 32),  tb, 0, stream>>>(Wk, wqkvT + 1024 * 1024, 1024, 1024);
  transpose_convert<<<dim3(32, 32),  tb, 0, stream>>>(Wv, wqkvT + 2048 * 1024, 1024, 1024);
  transpose_convert<<<dim3(32, 32),  tb, 0, stream>>>(Wo, woT, 1024, 1024);
  transpose_convert<<<dim3(128, 32), tb, 0, stream>>>(W1, w1T, 1024, 4096);
  transpose_convert<<<dim3(32, 128), tb, 0, stream>>>(W2, w2T, 4096, 1024);

  ln_kernel<<<8192, 256, 0, stream>>>(x, hb, ln1a, ln1b);

  // QKV merged: M=8192, N=3072, K=1024 -> 64 x 12 = 768 WGs
  gemm_pipe<MODE_QKV><<<768, 512, 0, stream>>>(
      hb, wqkvT, bq, bk, bv, nullptr, qb, kb, vPb, 8192, 3072, 1024);

  attn_kernel<<<dim3(64, 16), 256, 0, stream>>>(qb, kb, vPb, mask, ctx);

  // WO: M=8192, N=1024, K=1024 -> 64 x 4 = 256 WGs
  gemm_pipe<MODE_RES><<<256, 512, 0, stream>>>(
      ctx, woT, bo, nullptr, nullptr, x, xout, nullptr, nullptr, 8192, 1024, 1024);

  ln_kernel<<<8192, 256, 0, stream>>>(xout, hb, ln2a, ln2b);

  // FFN1: M=8192, N=4096, K=1024 -> 64 x 16 = 1024 WGs
  gemm_pipe<MODE_FFN1><<<1024, 512, 0, stream>>>(
      hb, w1T, b1, nullptr, nullptr, nullptr, gb, nullptr, nullptr, 8192, 4096, 1024);

  // FFN2: M=8192, N=1024, K=4096 -> 64 x 4 = 256 WGs
  gemm_pipe<MODE_RES><<<256, 512, 0, stream>>>(
      gb, w2T, b2, nullptr, nullptr, xout, xout, nullptr, nullptr, 8192, 1024, 4096);
}

// Round 9
// 429.525 us; speedup vs baseline: 1.1919x; 1.0465x over previous
//
#include <hip/hip_runtime.h>

typedef __attribute__((ext_vector_type(8))) short v8s;
typedef __attribute__((ext_vector_type(8))) unsigned short v8u;
typedef __attribute__((ext_vector_type(4))) unsigned short v4u;
typedef __attribute__((ext_vector_type(4))) float f32x4;

#define DEV __device__ __forceinline__

DEV unsigned short f2bf(float f) {
  union { float f; unsigned u; } v; v.f = f;
  unsigned r = v.u + 0x7fffu + ((v.u >> 16) & 1u);
  return (unsigned short)(r >> 16);
}

DEV void gload16(const unsigned short* g, unsigned short* l) {
  __builtin_amdgcn_global_load_lds(
      (const __attribute__((address_space(1))) unsigned int*)g,
      (__attribute__((address_space(3))) unsigned int*)l, 16, 0, 0);
}

#define SL2E 0.1803368801111204f  // 0.125 * log2(e)

// ------------------------------------------------------------------
// LayerNorm -> bf16
// ------------------------------------------------------------------
__global__ __launch_bounds__(256) void ln_kernel(
    const float* __restrict__ x, unsigned short* __restrict__ h,
    const float* __restrict__ alpha, const float* __restrict__ beta)
{
  int row = blockIdx.x;
  int tid = threadIdx.x;
  const float4* xr = reinterpret_cast<const float4*>(x + (size_t)row * 1024);
  float4 v = xr[tid];
  float s  = v.x + v.y + v.z + v.w;
  float ss = v.x * v.x + v.y * v.y + v.z * v.z + v.w * v.w;
#pragma unroll
  for (int off = 1; off < 64; off <<= 1) {
    s  += __shfl_xor(s, off);
    ss += __shfl_xor(ss, off);
  }
  __shared__ float ps[4][2];
  int wid = tid >> 6, lane = tid & 63;
  if (lane == 0) { ps[wid][0] = s; ps[wid][1] = ss; }
  __syncthreads();
  s  = ps[0][0] + ps[1][0] + ps[2][0] + ps[3][0];
  ss = ps[0][1] + ps[1][1] + ps[2][1] + ps[3][1];
  float mean = s * (1.0f / 1024.0f);
  float var  = (ss - 1024.0f * mean * mean) * (1.0f / 1023.0f);
  float inv  = 1.0f / (sqrtf(fmaxf(var, 0.0f)) + 1e-6f);
  float a = alpha[0], b = beta[0];
  v4u o;
  o[0] = f2bf(a * ((v.x - mean) * inv) + b);
  o[1] = f2bf(a * ((v.y - mean) * inv) + b);
  o[2] = f2bf(a * ((v.z - mean) * inv) + b);
  o[3] = f2bf(a * ((v.w - mean) * inv) + b);
  *reinterpret_cast<v4u*>(h + (size_t)row * 1024 + tid * 4) = o;
}

// ------------------------------------------------------------------
// fp32 W[K][N] -> bf16 Wt[N][K]
// ------------------------------------------------------------------
__global__ __launch_bounds__(256) void transpose_convert(
    const float* __restrict__ W, unsigned short* __restrict__ Wt, int K, int N)
{
  __shared__ float t[32][33];
  int n0 = blockIdx.x * 32, k0 = blockIdx.y * 32;
  int tx = threadIdx.x, ty = threadIdx.y;
#pragma unroll
  for (int i = 0; i < 4; ++i)
    t[ty + i * 8][tx] = W[(size_t)(k0 + ty + i * 8) * N + n0 + tx];
  __syncthreads();
#pragma unroll
  for (int i = 0; i < 4; ++i)
    Wt[(size_t)(n0 + ty + i * 8) * K + k0 + tx] = f2bf(t[tx][ty + i * 8]);
}

// ------------------------------------------------------------------
// Pipelined bf16 GEMM (128x256, BK=64, ring-3, counted vmcnt(6),
// ONE barrier per K-tile). 8 waves 2M x 4N, per-wave 64x64.
// ------------------------------------------------------------------
enum { MODE_QKV = 0, MODE_RES = 2, MODE_FFN1 = 3 };

#define BUF_ELEMS ((128 + 256) * 64)

DEV void stage_part(const unsigned short* Aptr, const unsigned short* Bptr,
                    unsigned short* buf, int K, int part, int wid, int lane)
{
  {
    int d = (part * 8 + wid) * 64 + lane;
    int r = d >> 3, p = d & 7;
    gload16(Aptr + (size_t)r * K + 8 * (p ^ (r & 7)),
            buf + (size_t)(part * 8 + wid) * 512);
  }
#pragma unroll
  for (int j = 0; j < 2; ++j) {
    int ib = part * 2 + j;
    int d = (ib * 8 + wid) * 64 + lane;
    int r = d >> 3, p = d & 7;
    gload16(Bptr + (size_t)r * K + 8 * (p ^ (r & 7)),
            buf + 128 * 64 + (size_t)(ib * 8 + wid) * 512);
  }
}

template <int MODE>
__global__ __launch_bounds__(512, 2) void gemm_pipe(
    const unsigned short* __restrict__ A, const unsigned short* __restrict__ Bt,
    const float* __restrict__ bias0, const float* __restrict__ bias1,
    const float* __restrict__ bias2, const float* __restrict__ resid,
    void* __restrict__ o0, void* __restrict__ o1, void* __restrict__ o2,
    int M, int N, int K)
{
  __shared__ unsigned short lds[3 * BUF_ELEMS];

  int nbx = M >> 7, nwg = gridDim.x;
  int lin = blockIdx.x;
  int qq = nwg >> 3, rr = nwg & 7;
  int xcd = lin & 7, idx = lin >> 3;
  int swz = (xcd < rr ? xcd * (qq + 1) : rr * (qq + 1) + (xcd - rr) * qq) + idx;
  int bx = swz % nbx, by = swz / nbx;

  int tid = threadIdx.x, lane = tid & 63, wid = tid >> 6;
  int wm = wid >> 2, wn = wid & 3;
  int g = lane >> 4, c0 = lane & 15;
  int rowBase = bx * 128, colBase = by * 256;

  const unsigned short* Ab = A  + (size_t)rowBase * K;
  const unsigned short* Bb = Bt + (size_t)colBase * K;
  int NT = K >> 6;

  f32x4 acc[4][4];
#pragma unroll
  for (int m = 0; m < 4; ++m)
#pragma unroll
    for (int n = 0; n < 4; ++n) acc[m][n] = (f32x4){0.f, 0.f, 0.f, 0.f};

  stage_part(Ab, Bb, lds, K, 0, wid, lane);
  stage_part(Ab, Bb, lds, K, 1, wid, lane);
  stage_part(Ab + 64, Bb + 64, lds + BUF_ELEMS, K, 0, wid, lane);
  stage_part(Ab + 64, Bb + 64, lds + BUF_ELEMS, K, 1, wid, lane);
  asm volatile("s_waitcnt vmcnt(6)" ::: "memory");
  __builtin_amdgcn_s_barrier();
  asm volatile("" ::: "memory");

  int cur = 0;
  for (int t = 0; t < NT; ++t) {
    const char* Abuf = (const char*)(lds + cur * BUF_ELEMS);
    const char* Bbuf = Abuf + 128 * 128;
    int nxt2 = cur + 2; if (nxt2 >= 3) nxt2 -= 3;
    unsigned short* sbuf = lds + nxt2 * BUF_ELEMS;
    bool doStage = (t + 2 < NT);
    int ks_ = (t + 2) << 6;
    int e = (c0 & 7) << 4;

#pragma unroll
    for (int ph = 0; ph < 2; ++ph) {
      v8s af[4], bfr[4];
#pragma unroll
      for (int m = 0; m < 4; ++m)
        af[m] = *reinterpret_cast<const v8s*>(
            Abuf + (wm * 64 + m * 16 + c0) * 128 + ((ph * 64 + g * 16) ^ e));
#pragma unroll
      for (int n = 0; n < 4; ++n)
        bfr[n] = *reinterpret_cast<const v8s*>(
            Bbuf + (wn * 64 + n * 16 + c0) * 128 + ((ph * 64 + g * 16) ^ e));

      if (doStage) stage_part(Ab + ks_, Bb + ks_, sbuf, K, ph, wid, lane);

      __builtin_amdgcn_s_setprio(1);
#pragma unroll
      for (int m = 0; m < 4; ++m)
#pragma unroll
        for (int n = 0; n < 4; ++n)
          acc[m][n] = __builtin_amdgcn_mfma_f32_16x16x32_bf16(
              af[m], bfr[n], acc[m][n], 0, 0, 0);
      __builtin_amdgcn_s_setprio(0);
    }

    if (doStage)            asm volatile("s_waitcnt vmcnt(6)" ::: "memory");
    else if (t + 1 < NT)    asm volatile("s_waitcnt vmcnt(0)" ::: "memory");
    __builtin_amdgcn_sched_barrier(0);
    __builtin_amdgcn_s_barrier();
    asm volatile("" ::: "memory");
    cur = cur + 1; if (cur >= 3) cur -= 3;
  }

#pragma unroll
  for (int mf = 0; mf < 4; ++mf) {
#pragma unroll
    for (int nf = 0; nf < 4; ++nf) {
#pragma unroll
      for (int r = 0; r < 4; ++r) {
        int row = rowBase + wm * 64 + mf * 16 + g * 4 + r;
        int col = colBase + wn * 64 + nf * 16 + c0;
        float v = acc[mf][nf][r];
        if constexpr (MODE == MODE_QKV) {
          int sect = colBase >> 10;
          int cs = col & 1023;
          const float* bp = sect == 0 ? bias0 : (sect == 1 ? bias1 : bias2);
          v += bp[cs];
          int hh = cs >> 6, d = cs & 63;
          int b = row >> 11, sI = row & 2047;
          size_t bh = (size_t)(b * 16 + hh);
          if (sect == 0) {
            ((unsigned short*)o0)[(bh * 2048 + sI) * 64 + d] = f2bf(v * SL2E);
          } else if (sect == 1) {
            ((unsigned short*)o1)[(bh * 2048 + sI) * 64 + d] = f2bf(v);
          } else {
            int k6 = sI & 63;
            int slot = ((k6 >> 5) << 5) | (((k6 >> 2) & 3) << 3) |
                       (((k6 >> 4) & 1) << 2) | (k6 & 3);
            int e2 = slot ^ ((d & 7) << 3);
            ((unsigned short*)o2)[((bh * 32 + (sI >> 6)) * 64 + d) * 64 + e2] = f2bf(v);
          }
        } else if constexpr (MODE == MODE_RES) {
          v += bias0[col];
          ((float*)o0)[(size_t)row * N + col] = resid[(size_t)row * N + col] + v;
        } else {
          v += bias0[col];
          ((unsigned short*)o0)[(size_t)row * N + col] = f2bf(fmaxf(v, 0.0f));
        }
      }
    }
  }
}

// ------------------------------------------------------------------
// 256x256 FFN1 GEMM: BK=64, 2 LDS buffers (128KB), per-wave 128x64,
// stage split across phases, drain + ONE barrier per tile.
// ------------------------------------------------------------------
__global__ __launch_bounds__(512, 1) void gemm_ffn1_256(
    const unsigned short* __restrict__ A, const unsigned short* __restrict__ Bt,
    const float* __restrict__ bias, unsigned short* __restrict__ out,
    int M, int N, int K)
{
  __shared__ unsigned short lds[2][512 * 64];

  int nbx = M >> 8, nwg = gridDim.x;
  int lin = blockIdx.x;
  int qq = nwg >> 3, rr = nwg & 7;
  int xcd = lin & 7, idx = lin >> 3;
  int swz = (xcd < rr ? xcd * (qq + 1) : rr * (qq + 1) + (xcd - rr) * qq) + idx;
  int bx = swz % nbx, by = swz / nbx;

  int tid = threadIdx.x, lane = tid & 63, wid = tid >> 6;
  int wm = wid >> 2, wn = wid & 3;
  int g = lane >> 4, c0 = lane & 15;
  int rowBase = bx * 256, colBase = by * 256;

  const unsigned short* Ab = A  + (size_t)rowBase * K;
  const unsigned short* Bb = Bt + (size_t)colBase * K;
  int NT = K >> 6;

  // staging: 8 granules/thread, q = i*512 + tid; i<4 -> A, else B
  const unsigned short* src[8]; int dq[8];
#pragma unroll
  for (int i = 0; i < 8; ++i) {
    int q = i * 512 + tid;
    dq[i] = q;
    if (i < 4) {
      int r = q >> 3, p = q & 7;
      src[i] = Ab + (size_t)r * K + 8 * (p ^ (r & 7));
    } else {
      int qb2 = q - 2048, r = qb2 >> 3, p = qb2 & 7;
      src[i] = Bb + (size_t)r * K + 8 * (p ^ (r & 7));
    }
  }

  f32x4 acc[8][4];
#pragma unroll
  for (int m = 0; m < 8; ++m)
#pragma unroll
    for (int n = 0; n < 4; ++n) acc[m][n] = (f32x4){0.f, 0.f, 0.f, 0.f};

#define STG256(tt, lo, hi) do { \
    unsigned short* sb_ = &lds[(tt) & 1][0]; int ko_ = (tt) << 6; \
    _Pragma("unroll") for (int i = lo; i < hi; ++i) gload16(src[i] + ko_, sb_ + dq[i] * 8); \
  } while (0)

  STG256(0, 0, 8);
  asm volatile("s_waitcnt vmcnt(0)" ::: "memory");
  __builtin_amdgcn_s_barrier();
  asm volatile("" ::: "memory");

  for (int t = 0; t < NT; ++t) {
    const char* buf = (const char*)&lds[t & 1][0];
    bool more = (t + 1 < NT);
    int e = (c0 & 7) << 4;

#pragma unroll
    for (int ph = 0; ph < 2; ++ph) {
      v8s af[8], bfr[4];
#pragma unroll
      for (int m = 0; m < 8; ++m) {
        int row = wm * 128 + m * 16 + c0;
        af[m] = *reinterpret_cast<const v8s*>(
            buf + row * 128 + ((ph * 64 + g * 16) ^ ((row & 7) << 4)));
      }
#pragma unroll
      for (int n = 0; n < 4; ++n) {
        int row = wn * 64 + n * 16 + c0;
        bfr[n] = *reinterpret_cast<const v8s*>(
            buf + 32768 + row * 128 + ((ph * 64 + g * 16) ^ ((row & 7) << 4)));
      }

      if (more) { if (ph == 0) STG256(t + 1, 0, 4); else STG256(t + 1, 4, 8); }

      __builtin_amdgcn_s_setprio(1);
#pragma unroll
      for (int m = 0; m < 8; ++m)
#pragma unroll
        for (int n = 0; n < 4; ++n)
          acc[m][n] = __builtin_amdgcn_mfma_f32_16x16x32_bf16(
              af[m], bfr[n], acc[m][n], 0, 0, 0);
      __builtin_amdgcn_s_setprio(0);
    }

    if (more) asm volatile("s_waitcnt vmcnt(0)" ::: "memory");
    __builtin_amdgcn_sched_barrier(0);
    __builtin_amdgcn_s_barrier();
    asm volatile("" ::: "memory");
  }
#undef STG256

#pragma unroll
  for (int mf = 0; mf < 8; ++mf) {
#pragma unroll
    for (int nf = 0; nf < 4; ++nf) {
#pragma unroll
      for (int r = 0; r < 4; ++r) {
        int row = rowBase + wm * 128 + mf * 16 + g * 4 + r;
        int col = colBase + wn * 64 + nf * 16 + c0;
        float v = acc[mf][nf][r] + bias[col];
        out[(size_t)row * N + col] = f2bf(fmaxf(v, 0.0f));
      }
    }
  }
}

// ------------------------------------------------------------------
// Flash attention v7: QBLK=128, ring-3 K/V (2-deep prefetch, counted
// vmcnt(4), one raw barrier/tile), LDS mask bias (bf16) + block-wide
// all-valid flag, no-max softmax p=exp2(s) (constant cancels in O).
// ------------------------------------------------------------------
__global__ __launch_bounds__(256) void attn_kernel(
    const unsigned short* __restrict__ q, const unsigned short* __restrict__ k,
    const unsigned short* __restrict__ vP, const int* __restrict__ mask,
    unsigned short* __restrict__ ctx)
{
  const int S = 2048, DK = 64, NT = 32;
  int bh = blockIdx.x;
  int b = bh >> 4, hh = bh & 15;
  int qbase = blockIdx.y * 128;
  int tid = threadIdx.x, lane = tid & 63, wid = tid >> 6;
  int g = lane >> 4, c0 = lane & 15;

  __shared__ unsigned short Ks[3 * 4096];
  __shared__ unsigned short Vs[3 * 4096];
  __shared__ unsigned short Mb[2048];

  const unsigned short* qb  = q  + (size_t)bh * S * DK;
  const unsigned short* kb  = k  + (size_t)bh * S * DK;
  const unsigned short* vPb = vP + (size_t)bh * 32 * 4096;
  const int* mb = mask + b * S;

  // ---- mask bias -> LDS (bf16), block-wide all-valid flag ----
  const int4* mb4 = reinterpret_cast<const int4*>(mb);
  int4 ma = mb4[tid * 2], mc = mb4[tid * 2 + 1];
  unsigned short bneg = f2bf(-1e9f);
  v8u bw;
  bw[0] = ma.x ? 0 : bneg; bw[1] = ma.y ? 0 : bneg;
  bw[2] = ma.z ? 0 : bneg; bw[3] = ma.w ? 0 : bneg;
  bw[4] = mc.x ? 0 : bneg; bw[5] = mc.y ? 0 : bneg;
  bw[6] = mc.z ? 0 : bneg; bw[7] = mc.w ? 0 : bneg;
  *reinterpret_cast<v8u*>(&Mb[tid * 8]) = bw;
  int ok = (ma.x && ma.y && ma.z && ma.w && mc.x && mc.y && mc.z && mc.w) ? 1 : 0;
  int allValid = __syncthreads_and(ok);

  // ---- Q fragments ----
  int qrow = qbase + wid * 32 + c0;
  v8s aq[2][2];
#pragma unroll
  for (int s = 0; s < 2; ++s)
#pragma unroll
    for (int t = 0; t < 2; ++t)
      aq[s][t] = *reinterpret_cast<const v8s*>(
          &qb[(size_t)(qrow + s * 16) * DK + t * 32 + g * 8]);

  int i0 = tid, i1 = tid + 256;
  int r0 = i0 >> 3, m0 = i0 & 7;
  int r1 = i1 >> 3, m1 = i1 & 7;
  const unsigned short* ks0 = kb + (size_t)r0 * DK + 8 * (m0 ^ (r0 & 7));
  const unsigned short* ks1 = kb + (size_t)r1 * DK + 8 * (m1 ^ (r1 & 7));

  f32x4 acc[2][4];
#pragma unroll
  for (int s = 0; s < 2; ++s)
#pragma unroll
    for (int no = 0; no < 4; ++no) acc[s][no] = (f32x4){0.f, 0.f, 0.f, 0.f};
  float lsum0 = 0.f, lsum1 = 0.f;

#define ASTAGE(bi, tt) do { \
    unsigned short* kd = Ks + (bi) * 4096; unsigned short* vd = Vs + (bi) * 4096; \
    int ko = (tt) * 64 * DK; \
    gload16(ks0 + ko, kd + i0 * 8); gload16(ks1 + ko, kd + i1 * 8); \
    gload16(vPb + (tt) * 4096 + i0 * 8, vd + i0 * 8); \
    gload16(vPb + (tt) * 4096 + i1 * 8, vd + i1 * 8); \
  } while (0)

  // prologue: stage tiles 0,1
  ASTAGE(0, 0);
  ASTAGE(1, 1);
  asm volatile("s_waitcnt vmcnt(4)" ::: "memory");
  __builtin_amdgcn_s_barrier();
  asm volatile("" ::: "memory");

  int cur = 0, nx2 = 2;
  for (int t = 0; t < NT; ++t) {
    bool more2 = (t + 2 < NT);
    if (more2) ASTAGE(nx2, t + 2);
    const unsigned short* Kc = Ks + cur * 4096;
    const unsigned short* Vc = Vs + cur * 4096;

    // ---- QK^T for both q-sets ----
    float p0[16], p1[16];
#pragma unroll
    for (int n = 0; n < 4; ++n) {
      int kvr = n * 16 + c0;
      const char* krow = (const char*)(Kc + kvr * DK);
      int sw = (kvr & 7) << 4;
      v8s ak0 = *reinterpret_cast<const v8s*>(krow + ((g * 16) ^ sw));
      v8s ak1 = *reinterpret_cast<const v8s*>(krow + ((64 + g * 16) ^ sw));
      f32x4 s0 = (f32x4){0.f, 0.f, 0.f, 0.f};
      f32x4 s1 = (f32x4){0.f, 0.f, 0.f, 0.f};
      s0 = __builtin_amdgcn_mfma_f32_16x16x32_bf16(ak0, aq[0][0], s0, 0, 0, 0);
      s0 = __builtin_amdgcn_mfma_f32_16x16x32_bf16(ak1, aq[0][1], s0, 0, 0, 0);
      s1 = __builtin_amdgcn_mfma_f32_16x16x32_bf16(ak0, aq[1][0], s1, 0, 0, 0);
      s1 = __builtin_amdgcn_mfma_f32_16x16x32_bf16(ak1, aq[1][1], s1, 0, 0, 0);
#pragma unroll
      for (int r = 0; r < 4; ++r) { p0[n * 4 + r] = s0[r]; p1[n * 4 + r] = s1[r]; }
    }
    if (!allValid) {
#pragma unroll
      for (int n = 0; n < 4; ++n) {
        v4u mbv = *reinterpret_cast<const v4u*>(&Mb[t * 64 + n * 16 + g * 4]);
#pragma unroll
        for (int r = 0; r < 4; ++r) {
          union { unsigned u; float f; } cv; cv.u = ((unsigned)mbv[r]) << 16;
          p0[n * 4 + r] += cv.f; p1[n * 4 + r] += cv.f;
        }
      }
    }

    // ---- no-max softmax: p = exp2(s); constant scale cancels in O ----
    float ts0 = 0.f, ts1 = 0.f;
#pragma unroll
    for (int i = 0; i < 16; ++i) {
      p0[i] = exp2f(p0[i]); ts0 += p0[i];
      p1[i] = exp2f(p1[i]); ts1 += p1[i];
    }
    lsum0 += ts0; lsum1 += ts1;

    // ---- pack P to bf16 ----
    v8s pb0[2], pb1[2];
#pragma unroll
    for (int c = 0; c < 2; ++c) {
      union { v8s s; unsigned u[4]; } k0, k1;
#pragma unroll
      for (int hp = 0; hp < 4; ++hp) {
        asm("v_cvt_pk_bf16_f32 %0, %1, %2"
            : "=v"(k0.u[hp]) : "v"(p0[c * 8 + 2 * hp]), "v"(p0[c * 8 + 2 * hp + 1]));
        asm("v_cvt_pk_bf16_f32 %0, %1, %2"
            : "=v"(k1.u[hp]) : "v"(p1[c * 8 + 2 * hp]), "v"(p1[c * 8 + 2 * hp + 1]));
      }
      pb0[c] = k0.s; pb1[c] = k1.s;
    }

    // ---- PV ----
#pragma unroll
    for (int c = 0; c < 2; ++c) {
#pragma unroll
      for (int no = 0; no < 4; ++no) {
        int d = no * 16 + c0;
        v8s av = *reinterpret_cast<const v8s*>(
            (const char*)(Vc + d * 64) + ((c * 64 + g * 16) ^ ((d & 7) << 4)));
        acc[0][no] = __builtin_amdgcn_mfma_f32_16x16x32_bf16(av, pb0[c], acc[0][no], 0, 0, 0);
        acc[1][no] = __builtin_amdgcn_mfma_f32_16x16x32_bf16(av, pb1[c], acc[1][no], 0, 0, 0);
      }
    }

    if (more2)              asm volatile("s_waitcnt vmcnt(4)" ::: "memory");
    else if (t + 1 < NT)    asm volatile("s_waitcnt vmcnt(0)" ::: "memory");
    __builtin_amdgcn_sched_barrier(0);
    __builtin_amdgcn_s_barrier();
    asm volatile("" ::: "memory");
    cur = (cur + 1 < 3) ? cur + 1 : 0;
    nx2 = (nx2 + 1 < 3) ? nx2 + 1 : 0;
  }
#undef ASTAGE

  lsum0 += __shfl_xor(lsum0, 16); lsum0 += __shfl_xor(lsum0, 32);
  lsum1 += __shfl_xor(lsum1, 16); lsum1 += __shfl_xor(lsum1, 32);
  float lrow[2] = {lsum0, lsum1};

#pragma unroll
  for (int s = 0; s < 2; ++s) {
    float inv = 1.0f / fmaxf(lrow[s], 1e-30f);
#pragma unroll
    for (int no = 0; no < 4; ++no) {
      v4u o;
      o[0] = f2bf(acc[s][no][0] * inv);
      o[1] = f2bf(acc[s][no][1] * inv);
      o[2] = f2bf(acc[s][no][2] * inv);
      o[3] = f2bf(acc[s][no][3] * inv);
      *reinterpret_cast<v4u*>(
          &ctx[(size_t)(b * S + qrow + s * 16) * 1024 + hh * 64 + no * 16 + g * 4]) = o;
    }
  }
}

// ------------------------------------------------------------------
extern "C" void kernel_launch(void* const* d_in, const int* in_sizes, int n_in,
                              void* d_out, int out_size, void* d_ws, size_t ws_size,
                              hipStream_t stream)
{
  (void)in_sizes; (void)n_in; (void)out_size; (void)ws_size;
  const float* x    = (const float*)d_in[0];
  const int*   mask = (const int*)d_in[1];
  const float* Wq = (const float*)d_in[2];  const float* bq = (const float*)d_in[3];
  const float* Wk = (const float*)d_in[4];  const float* bk = (const float*)d_in[5];
  const float* Wv = (const float*)d_in[6];  const float* bv = (const float*)d_in[7];
  const float* Wo = (const float*)d_in[8];  const float* bo = (const float*)d_in[9];
  const float* W1 = (const float*)d_in[10]; const float* b1 = (const float*)d_in[11];
  const float* W2 = (const float*)d_in[12]; const float* b2 = (const float*)d_in[13];
  const float* ln1a = (const float*)d_in[14]; const float* ln1b = (const float*)d_in[15];
  const float* ln2a = (const float*)d_in[16]; const float* ln2b = (const float*)d_in[17];

  char* ws = (char*)d_ws;
  const size_t MB = (size_t)1 << 20;
  unsigned short* wqkvT = (unsigned short*)(ws + 0 * MB);  // [3072][1024]
  unsigned short* woT = (unsigned short*)(ws + 6 * MB);    // [1024][1024]
  unsigned short* w1T = (unsigned short*)(ws + 8 * MB);    // [4096][1024]
  unsigned short* w2T = (unsigned short*)(ws + 16 * MB);   // [1024][4096]
  unsigned short* hb  = (unsigned short*)(ws + 24 * MB);   // LN out, 8192x1024
  unsigned short* qb  = (unsigned short*)(ws + 40 * MB);   // [bh][S][64], pre-scaled
  unsigned short* kb  = (unsigned short*)(ws + 56 * MB);   // [bh][S][64]
  unsigned short* vPb = (unsigned short*)(ws + 72 * MB);   // [bh][32][64][64] permuted
  unsigned short* ctx = (unsigned short*)(ws + 88 * MB);   // 8192x1024
  unsigned short* gb  = (unsigned short*)(ws + 40 * MB);   // FFN mid (aliases dead bufs)
  float* xout = (float*)d_out;

  dim3 tb(32, 8);
  transpose_convert<<<dim3(32, 32),  tb, 0, stream>>>(Wq, wqkvT,               1024, 1024);
  transpose_convert<<<dim3(32, 32),  tb, 0, stream>>>(Wk, wqkvT + 1024 * 1024, 1024, 1024);
  transpose_convert<<<dim3(32, 32),  tb, 0, stream>>>(Wv, wqkvT + 2048 * 1024, 1024, 1024);
  transpose_convert<<<dim3(32, 32),  tb, 0, stream>>>(Wo, woT, 1024, 1024);
  transpose_convert<<<dim3(128, 32), tb, 0, stream>>>(W1, w1T, 1024, 4096);
  transpose_convert<<<dim3(32, 128), tb, 0, stream>>>(W2, w2T, 4096, 1024);

  ln_kernel<<<8192, 256, 0, stream>>>(x, hb, ln1a, ln1b);

  // QKV merged: M=8192, N=3072 -> 64 x 12 = 768 WGs
  gemm_pipe<MODE_QKV><<<768, 512, 0, stream>>>(
      hb, wqkvT, bq, bk, bv, nullptr, qb, kb, vPb, 8192, 3072, 1024);

  attn_kernel<<<dim3(64, 16), 256, 0, stream>>>(qb, kb, vPb, mask, ctx);

  // WO: 64 x 4 = 256 WGs
  gemm_pipe<MODE_RES><<<256, 512, 0, stream>>>(
      ctx, woT, bo, nullptr, nullptr, x, xout, nullptr, nullptr, 8192, 1024, 1024);

  ln_kernel<<<8192, 256, 0, stream>>>(xout, hb, ln2a, ln2b);

  // FFN1: 256x256 tile -> 32 x 16 = 512 WGs
  gemm_ffn1_256<<<512, 512, 0, stream>>>(hb, w1T, b1, gb, 8192, 4096, 1024);

  // FFN2: 64 x 4 = 256 WGs
  gemm_pipe<MODE_RES><<<256, 512, 0, stream>>>(
      gb, w2T, b2, nullptr, nullptr, xout, xout, nullptr, nullptr, 8192, 1024, 4096);
}

// Round 10
// 401.418 us; speedup vs baseline: 1.2754x; 1.0700x over previous
//
#include <hip/hip_runtime.h>

typedef __attribute__((ext_vector_type(8))) short v8s;
typedef __attribute__((ext_vector_type(8))) unsigned short v8u;
typedef __attribute__((ext_vector_type(4))) unsigned short v4u;
typedef __attribute__((ext_vector_type(4))) float f32x4;

#define DEV __device__ __forceinline__

DEV unsigned short f2bf(float f) {
  union { float f; unsigned u; } v; v.f = f;
  unsigned r = v.u + 0x7fffu + ((v.u >> 16) & 1u);
  return (unsigned short)(r >> 16);
}

DEV float fexp2(float x) {
  float r; asm("v_exp_f32 %0, %1" : "=v"(r) : "v"(x)); return r;
}

DEV void gload16(const unsigned short* g, unsigned short* l) {
  __builtin_amdgcn_global_load_lds(
      (const __attribute__((address_space(1))) unsigned int*)g,
      (__attribute__((address_space(3))) unsigned int*)l, 16, 0, 0);
}

#define SL2E 0.1803368801111204f  // 0.125 * log2(e)

// ------------------------------------------------------------------
// LayerNorm -> bf16
// ------------------------------------------------------------------
__global__ __launch_bounds__(256) void ln_kernel(
    const float* __restrict__ x, unsigned short* __restrict__ h,
    const float* __restrict__ alpha, const float* __restrict__ beta)
{
  int row = blockIdx.x;
  int tid = threadIdx.x;
  const float4* xr = reinterpret_cast<const float4*>(x + (size_t)row * 1024);
  float4 v = xr[tid];
  float s  = v.x + v.y + v.z + v.w;
  float ss = v.x * v.x + v.y * v.y + v.z * v.z + v.w * v.w;
#pragma unroll
  for (int off = 1; off < 64; off <<= 1) {
    s  += __shfl_xor(s, off);
    ss += __shfl_xor(ss, off);
  }
  __shared__ float ps[4][2];
  int wid = tid >> 6, lane = tid & 63;
  if (lane == 0) { ps[wid][0] = s; ps[wid][1] = ss; }
  __syncthreads();
  s  = ps[0][0] + ps[1][0] + ps[2][0] + ps[3][0];
  ss = ps[0][1] + ps[1][1] + ps[2][1] + ps[3][1];
  float mean = s * (1.0f / 1024.0f);
  float var  = (ss - 1024.0f * mean * mean) * (1.0f / 1023.0f);
  float inv  = 1.0f / (sqrtf(fmaxf(var, 0.0f)) + 1e-6f);
  float a = alpha[0], b = beta[0];
  v4u o;
  o[0] = f2bf(a * ((v.x - mean) * inv) + b);
  o[1] = f2bf(a * ((v.y - mean) * inv) + b);
  o[2] = f2bf(a * ((v.z - mean) * inv) + b);
  o[3] = f2bf(a * ((v.w - mean) * inv) + b);
  *reinterpret_cast<v4u*>(h + (size_t)row * 1024 + tid * 4) = o;
}

// ------------------------------------------------------------------
// fp32 W[K][N] -> bf16 Wt[N][K]
// ------------------------------------------------------------------
__global__ __launch_bounds__(256) void transpose_convert(
    const float* __restrict__ W, unsigned short* __restrict__ Wt, int K, int N)
{
  __shared__ float t[32][33];
  int n0 = blockIdx.x * 32, k0 = blockIdx.y * 32;
  int tx = threadIdx.x, ty = threadIdx.y;
#pragma unroll
  for (int i = 0; i < 4; ++i)
    t[ty + i * 8][tx] = W[(size_t)(k0 + ty + i * 8) * N + n0 + tx];
  __syncthreads();
#pragma unroll
  for (int i = 0; i < 4; ++i)
    Wt[(size_t)(n0 + ty + i * 8) * K + k0 + tx] = f2bf(t[tx][ty + i * 8]);
}

enum { MODE_QKV = 0, MODE_RES = 2, MODE_FFN1 = 3 };

// ------------------------------------------------------------------
// 256x256 GEMM: BK=64, 2 LDS buffers (128KB), 8 waves 2Mx4N,
// per-wave 128x64 (24 b128 reads / 64 MFMA), all staging loads issued
// at phase-0 start, drain + ONE barrier per tile. MODE_QKV/MODE_FFN1.
// ------------------------------------------------------------------
template <int MODE>
__global__ __launch_bounds__(512, 1) void gemm_256(
    const unsigned short* __restrict__ A, const unsigned short* __restrict__ Bt,
    const float* __restrict__ bias0, const float* __restrict__ bias1,
    const float* __restrict__ bias2,
    void* __restrict__ o0, void* __restrict__ o1, void* __restrict__ o2,
    int M, int N, int K)
{
  __shared__ unsigned short lds[2][512 * 64];

  int nbx = M >> 8, nwg = gridDim.x;
  int lin = blockIdx.x;
  int qq = nwg >> 3, rr = nwg & 7;
  int xcd = lin & 7, idx = lin >> 3;
  int swz = (xcd < rr ? xcd * (qq + 1) : rr * (qq + 1) + (xcd - rr) * qq) + idx;
  int bx = swz % nbx, by = swz / nbx;

  int tid = threadIdx.x, lane = tid & 63, wid = tid >> 6;
  int wm = wid >> 2, wn = wid & 3;
  int g = lane >> 4, c0 = lane & 15;
  int rowBase = bx * 256, colBase = by * 256;

  const unsigned short* Ab = A  + (size_t)rowBase * K;
  const unsigned short* Bb = Bt + (size_t)colBase * K;
  int NT = K >> 6;

  const unsigned short* src[8]; int dq[8];
#pragma unroll
  for (int i = 0; i < 8; ++i) {
    int q = i * 512 + tid;
    dq[i] = q;
    if (i < 4) {
      int r = q >> 3, p = q & 7;
      src[i] = Ab + (size_t)r * K + 8 * (p ^ (r & 7));
    } else {
      int qb2 = q - 2048, r = qb2 >> 3, p = qb2 & 7;
      src[i] = Bb + (size_t)r * K + 8 * (p ^ (r & 7));
    }
  }

  f32x4 acc[8][4];
#pragma unroll
  for (int m = 0; m < 8; ++m)
#pragma unroll
    for (int n = 0; n < 4; ++n) acc[m][n] = (f32x4){0.f, 0.f, 0.f, 0.f};

#define STG256(tt) do { \
    unsigned short* sb_ = &lds[(tt) & 1][0]; int ko_ = (tt) << 6; \
    _Pragma("unroll") for (int i = 0; i < 8; ++i) gload16(src[i] + ko_, sb_ + dq[i] * 8); \
  } while (0)

  STG256(0);
  asm volatile("s_waitcnt vmcnt(0)" ::: "memory");
  __builtin_amdgcn_s_barrier();
  asm volatile("" ::: "memory");

  for (int t = 0; t < NT; ++t) {
    const char* buf = (const char*)&lds[t & 1][0];
    bool more = (t + 1 < NT);
    if (more) STG256(t + 1);
    int e = (c0 & 7) << 4;

#pragma unroll
    for (int ph = 0; ph < 2; ++ph) {
      v8s af[8], bfr[4];
#pragma unroll
      for (int m = 0; m < 8; ++m) {
        int row = wm * 128 + m * 16 + c0;
        af[m] = *reinterpret_cast<const v8s*>(
            buf + row * 128 + ((ph * 64 + g * 16) ^ e));
      }
#pragma unroll
      for (int n = 0; n < 4; ++n) {
        int row = wn * 64 + n * 16 + c0;
        bfr[n] = *reinterpret_cast<const v8s*>(
            buf + 32768 + row * 128 + ((ph * 64 + g * 16) ^ e));
      }

      __builtin_amdgcn_s_setprio(1);
#pragma unroll
      for (int m = 0; m < 8; ++m)
#pragma unroll
        for (int n = 0; n < 4; ++n)
          acc[m][n] = __builtin_amdgcn_mfma_f32_16x16x32_bf16(
              af[m], bfr[n], acc[m][n], 0, 0, 0);
      __builtin_amdgcn_s_setprio(0);
    }

    if (more) asm volatile("s_waitcnt vmcnt(0)" ::: "memory");
    __builtin_amdgcn_sched_barrier(0);
    __builtin_amdgcn_s_barrier();
    asm volatile("" ::: "memory");
  }
#undef STG256

#pragma unroll
  for (int mf = 0; mf < 8; ++mf) {
#pragma unroll
    for (int nf = 0; nf < 4; ++nf) {
#pragma unroll
      for (int r = 0; r < 4; ++r) {
        int row = rowBase + wm * 128 + mf * 16 + g * 4 + r;
        int col = colBase + wn * 64 + nf * 16 + c0;
        float v = acc[mf][nf][r];
        if constexpr (MODE == MODE_QKV) {
          int sect = colBase >> 10;
          int cs = col & 1023;
          const float* bp = sect == 0 ? bias0 : (sect == 1 ? bias1 : bias2);
          v += bp[cs];
          int hh = cs >> 6, d = cs & 63;
          int b = row >> 11, sI = row & 2047;
          size_t bh = (size_t)(b * 16 + hh);
          if (sect == 0) {
            ((unsigned short*)o0)[(bh * 2048 + sI) * 64 + d] = f2bf(v * SL2E);
          } else if (sect == 1) {
            ((unsigned short*)o1)[(bh * 2048 + sI) * 64 + d] = f2bf(v);
          } else {
            int k6 = sI & 63;
            int slot = ((k6 >> 5) << 5) | (((k6 >> 2) & 3) << 3) |
                       (((k6 >> 4) & 1) << 2) | (k6 & 3);
            int e2 = slot ^ ((d & 7) << 3);
            ((unsigned short*)o2)[((bh * 32 + (sI >> 6)) * 64 + d) * 64 + e2] = f2bf(v);
          }
        } else { // MODE_FFN1
          v += bias0[col];
          ((unsigned short*)o0)[(size_t)row * N + col] = f2bf(fmaxf(v, 0.0f));
        }
      }
    }
  }
}

// ------------------------------------------------------------------
// Pipelined bf16 GEMM (128x256, BK=64, ring-3, counted vmcnt(6),
// one barrier per K-tile). For WO / FFN2 (N=1024 shapes).
// ------------------------------------------------------------------
#define BUF_ELEMS ((128 + 256) * 64)

DEV void stage_part(const unsigned short* Aptr, const unsigned short* Bptr,
                    unsigned short* buf, int K, int part, int wid, int lane)
{
  {
    int d = (part * 8 + wid) * 64 + lane;
    int r = d >> 3, p = d & 7;
    gload16(Aptr + (size_t)r * K + 8 * (p ^ (r & 7)),
            buf + (size_t)(part * 8 + wid) * 512);
  }
#pragma unroll
  for (int j = 0; j < 2; ++j) {
    int ib = part * 2 + j;
    int d = (ib * 8 + wid) * 64 + lane;
    int r = d >> 3, p = d & 7;
    gload16(Bptr + (size_t)r * K + 8 * (p ^ (r & 7)),
            buf + 128 * 64 + (size_t)(ib * 8 + wid) * 512);
  }
}

__global__ __launch_bounds__(512, 2) void gemm_pipe_res(
    const unsigned short* __restrict__ A, const unsigned short* __restrict__ Bt,
    const float* __restrict__ bias0, const float* __restrict__ resid,
    float* __restrict__ o0, int M, int N, int K)
{
  __shared__ unsigned short lds[3 * BUF_ELEMS];

  int nbx = M >> 7, nwg = gridDim.x;
  int lin = blockIdx.x;
  int qq = nwg >> 3, rr = nwg & 7;
  int xcd = lin & 7, idx = lin >> 3;
  int swz = (xcd < rr ? xcd * (qq + 1) : rr * (qq + 1) + (xcd - rr) * qq) + idx;
  int bx = swz % nbx, by = swz / nbx;

  int tid = threadIdx.x, lane = tid & 63, wid = tid >> 6;
  int wm = wid >> 2, wn = wid & 3;
  int g = lane >> 4, c0 = lane & 15;
  int rowBase = bx * 128, colBase = by * 256;

  const unsigned short* Ab = A  + (size_t)rowBase * K;
  const unsigned short* Bb = Bt + (size_t)colBase * K;
  int NT = K >> 6;

  f32x4 acc[4][4];
#pragma unroll
  for (int m = 0; m < 4; ++m)
#pragma unroll
    for (int n = 0; n < 4; ++n) acc[m][n] = (f32x4){0.f, 0.f, 0.f, 0.f};

  stage_part(Ab, Bb, lds, K, 0, wid, lane);
  stage_part(Ab, Bb, lds, K, 1, wid, lane);
  stage_part(Ab + 64, Bb + 64, lds + BUF_ELEMS, K, 0, wid, lane);
  stage_part(Ab + 64, Bb + 64, lds + BUF_ELEMS, K, 1, wid, lane);
  asm volatile("s_waitcnt vmcnt(6)" ::: "memory");
  __builtin_amdgcn_s_barrier();
  asm volatile("" ::: "memory");

  int cur = 0;
  for (int t = 0; t < NT; ++t) {
    const char* Abuf = (const char*)(lds + cur * BUF_ELEMS);
    const char* Bbuf = Abuf + 128 * 128;
    int nxt2 = cur + 2; if (nxt2 >= 3) nxt2 -= 3;
    unsigned short* sbuf = lds + nxt2 * BUF_ELEMS;
    bool doStage = (t + 2 < NT);
    int ks_ = (t + 2) << 6;
    int e = (c0 & 7) << 4;

#pragma unroll
    for (int ph = 0; ph < 2; ++ph) {
      v8s af[4], bfr[4];
#pragma unroll
      for (int m = 0; m < 4; ++m)
        af[m] = *reinterpret_cast<const v8s*>(
            Abuf + (wm * 64 + m * 16 + c0) * 128 + ((ph * 64 + g * 16) ^ e));
#pragma unroll
      for (int n = 0; n < 4; ++n)
        bfr[n] = *reinterpret_cast<const v8s*>(
            Bbuf + (wn * 64 + n * 16 + c0) * 128 + ((ph * 64 + g * 16) ^ e));

      if (doStage) stage_part(Ab + ks_, Bb + ks_, sbuf, K, ph, wid, lane);

      __builtin_amdgcn_s_setprio(1);
#pragma unroll
      for (int m = 0; m < 4; ++m)
#pragma unroll
        for (int n = 0; n < 4; ++n)
          acc[m][n] = __builtin_amdgcn_mfma_f32_16x16x32_bf16(
              af[m], bfr[n], acc[m][n], 0, 0, 0);
      __builtin_amdgcn_s_setprio(0);
    }

    if (doStage)            asm volatile("s_waitcnt vmcnt(6)" ::: "memory");
    else if (t + 1 < NT)    asm volatile("s_waitcnt vmcnt(0)" ::: "memory");
    __builtin_amdgcn_sched_barrier(0);
    __builtin_amdgcn_s_barrier();
    asm volatile("" ::: "memory");
    cur = cur + 1; if (cur >= 3) cur -= 3;
  }

#pragma unroll
  for (int mf = 0; mf < 4; ++mf) {
#pragma unroll
    for (int nf = 0; nf < 4; ++nf) {
#pragma unroll
      for (int r = 0; r < 4; ++r) {
        int row = rowBase + wm * 64 + mf * 16 + g * 4 + r;
        int col = colBase + wn * 64 + nf * 16 + c0;
        float v = acc[mf][nf][r] + bias0[col];
        o0[(size_t)row * N + col] = resid[(size_t)row * N + col] + v;
      }
    }
  }
}

// ------------------------------------------------------------------
// Flash attention v8: QBLK=128, ring-3 K/V, counted vmcnt(4), raw
// v_exp_f32, saddr+voffset staging, LDS mask bias + all-valid flag.
// ------------------------------------------------------------------
__global__ __launch_bounds__(256) void attn_kernel(
    const unsigned short* __restrict__ q, const unsigned short* __restrict__ k,
    const unsigned short* __restrict__ vP, const int* __restrict__ mask,
    unsigned short* __restrict__ ctx)
{
  const int S = 2048, DK = 64, NT = 32;
  int bh = blockIdx.x;
  int b = bh >> 4, hh = bh & 15;
  int qbase = blockIdx.y * 128;
  int tid = threadIdx.x, lane = tid & 63, wid = tid >> 6;
  int g = lane >> 4, c0 = lane & 15;

  __shared__ unsigned short Ks[3 * 4096];
  __shared__ unsigned short Vs[3 * 4096];
  __shared__ unsigned short Mb[2048];

  const unsigned short* qb  = q  + (size_t)bh * S * DK;
  const unsigned short* kb  = k  + (size_t)bh * S * DK;
  const unsigned short* vPb = vP + (size_t)bh * 32 * 4096;
  const int* mb = mask + b * S;

  // ---- mask bias -> LDS (bf16), block-wide all-valid flag ----
  const int4* mb4 = reinterpret_cast<const int4*>(mb);
  int4 ma = mb4[tid * 2], mc = mb4[tid * 2 + 1];
  unsigned short bneg = f2bf(-1e9f);
  v8u bw;
  bw[0] = ma.x ? 0 : bneg; bw[1] = ma.y ? 0 : bneg;
  bw[2] = ma.z ? 0 : bneg; bw[3] = ma.w ? 0 : bneg;
  bw[4] = mc.x ? 0 : bneg; bw[5] = mc.y ? 0 : bneg;
  bw[6] = mc.z ? 0 : bneg; bw[7] = mc.w ? 0 : bneg;
  *reinterpret_cast<v8u*>(&Mb[tid * 8]) = bw;
  int ok = (ma.x && ma.y && ma.z && ma.w && mc.x && mc.y && mc.z && mc.w) ? 1 : 0;
  int allValid = __syncthreads_and(ok);

  // ---- Q fragments ----
  int qrow = qbase + wid * 32 + c0;
  v8s aq[2][2];
#pragma unroll
  for (int s = 0; s < 2; ++s)
#pragma unroll
    for (int t = 0; t < 2; ++t)
      aq[s][t] = *reinterpret_cast<const v8s*>(
          &qb[(size_t)(qrow + s * 16) * DK + t * 32 + g * 8]);

  // staging offsets (32-bit, lane-resident; base pointers stay scalar)
  int i0 = tid, i1 = tid + 256;
  int r0 = i0 >> 3, m0 = i0 & 7;
  int r1 = i1 >> 3, m1 = i1 & 7;
  int ko0 = r0 * DK + 8 * (m0 ^ (r0 & 7));
  int ko1 = r1 * DK + 8 * (m1 ^ (r1 & 7));

  f32x4 acc[2][4];
#pragma unroll
  for (int s = 0; s < 2; ++s)
#pragma unroll
    for (int no = 0; no < 4; ++no) acc[s][no] = (f32x4){0.f, 0.f, 0.f, 0.f};
  float lsum0 = 0.f, lsum1 = 0.f;

#define ASTAGE(bi, tt) do { \
    int tb_ = (tt) * 4096; \
    gload16(kb + tb_ + ko0, Ks + (bi) * 4096 + i0 * 8); \
    gload16(kb + tb_ + ko1, Ks + (bi) * 4096 + i1 * 8); \
    gload16(vPb + tb_ + i0 * 8, Vs + (bi) * 4096 + i0 * 8); \
    gload16(vPb + tb_ + i1 * 8, Vs + (bi) * 4096 + i1 * 8); \
  } while (0)

  ASTAGE(0, 0);
  ASTAGE(1, 1);
  asm volatile("s_waitcnt vmcnt(4)" ::: "memory");
  __builtin_amdgcn_s_barrier();
  asm volatile("" ::: "memory");

  int cur = 0, nx2 = 2;
  for (int t = 0; t < NT; ++t) {
    bool more2 = (t + 2 < NT);
    if (more2) ASTAGE(nx2, t + 2);
    const unsigned short* Kc = Ks + cur * 4096;
    const unsigned short* Vc = Vs + cur * 4096;

    // ---- QK^T for both q-sets ----
    float p0[16], p1[16];
#pragma unroll
    for (int n = 0; n < 4; ++n) {
      int kvr = n * 16 + c0;
      const char* krow = (const char*)(Kc + kvr * DK);
      int sw = (kvr & 7) << 4;
      v8s ak0 = *reinterpret_cast<const v8s*>(krow + ((g * 16) ^ sw));
      v8s ak1 = *reinterpret_cast<const v8s*>(krow + ((64 + g * 16) ^ sw));
      f32x4 s0 = (f32x4){0.f, 0.f, 0.f, 0.f};
      f32x4 s1 = (f32x4){0.f, 0.f, 0.f, 0.f};
      s0 = __builtin_amdgcn_mfma_f32_16x16x32_bf16(ak0, aq[0][0], s0, 0, 0, 0);
      s0 = __builtin_amdgcn_mfma_f32_16x16x32_bf16(ak1, aq[0][1], s0, 0, 0, 0);
      s1 = __builtin_amdgcn_mfma_f32_16x16x32_bf16(ak0, aq[1][0], s1, 0, 0, 0);
      s1 = __builtin_amdgcn_mfma_f32_16x16x32_bf16(ak1, aq[1][1], s1, 0, 0, 0);
#pragma unroll
      for (int r = 0; r < 4; ++r) { p0[n * 4 + r] = s0[r]; p1[n * 4 + r] = s1[r]; }
    }
    if (!allValid) {
#pragma unroll
      for (int n = 0; n < 4; ++n) {
        v4u mbv = *reinterpret_cast<const v4u*>(&Mb[t * 64 + n * 16 + g * 4]);
#pragma unroll
        for (int r = 0; r < 4; ++r) {
          union { unsigned u; float f; } cv; cv.u = ((unsigned)mbv[r]) << 16;
          p0[n * 4 + r] += cv.f; p1[n * 4 + r] += cv.f;
        }
      }
    }

    // ---- no-max softmax: p = exp2(s); constant scale cancels in O ----
    float ts0 = 0.f, ts1 = 0.f;
#pragma unroll
    for (int i = 0; i < 16; ++i) {
      p0[i] = fexp2(p0[i]); ts0 += p0[i];
      p1[i] = fexp2(p1[i]); ts1 += p1[i];
    }
    lsum0 += ts0; lsum1 += ts1;

    // ---- pack P to bf16 ----
    v8s pb0[2], pb1[2];
#pragma unroll
    for (int c = 0; c < 2; ++c) {
      union { v8s s; unsigned u[4]; } k0, k1;
#pragma unroll
      for (int hp = 0; hp < 4; ++hp) {
        asm("v_cvt_pk_bf16_f32 %0, %1, %2"
            : "=v"(k0.u[hp]) : "v"(p0[c * 8 + 2 * hp]), "v"(p0[c * 8 + 2 * hp + 1]));
        asm("v_cvt_pk_bf16_f32 %0, %1, %2"
            : "=v"(k1.u[hp]) : "v"(p1[c * 8 + 2 * hp]), "v"(p1[c * 8 + 2 * hp + 1]));
      }
      pb0[c] = k0.s; pb1[c] = k1.s;
    }

    // ---- PV ----
#pragma unroll
    for (int c = 0; c < 2; ++c) {
#pragma unroll
      for (int no = 0; no < 4; ++no) {
        int d = no * 16 + c0;
        v8s av = *reinterpret_cast<const v8s*>(
            (const char*)(Vc + d * 64) + ((c * 64 + g * 16) ^ ((d & 7) << 4)));
        acc[0][no] = __builtin_amdgcn_mfma_f32_16x16x32_bf16(av, pb0[c], acc[0][no], 0, 0, 0);
        acc[1][no] = __builtin_amdgcn_mfma_f32_16x16x32_bf16(av, pb1[c], acc[1][no], 0, 0, 0);
      }
    }

    if (more2)              asm volatile("s_waitcnt vmcnt(4)" ::: "memory");
    else if (t + 1 < NT)    asm volatile("s_waitcnt vmcnt(0)" ::: "memory");
    __builtin_amdgcn_sched_barrier(0);
    __builtin_amdgcn_s_barrier();
    asm volatile("" ::: "memory");
    cur = (cur + 1 < 3) ? cur + 1 : 0;
    nx2 = (nx2 + 1 < 3) ? nx2 + 1 : 0;
  }
#undef ASTAGE

  lsum0 += __shfl_xor(lsum0, 16); lsum0 += __shfl_xor(lsum0, 32);
  lsum1 += __shfl_xor(lsum1, 16); lsum1 += __shfl_xor(lsum1, 32);
  float lrow[2] = {lsum0, lsum1};

#pragma unroll
  for (int s = 0; s < 2; ++s) {
    float inv = 1.0f / fmaxf(lrow[s], 1e-30f);
#pragma unroll
    for (int no = 0; no < 4; ++no) {
      v4u o;
      o[0] = f2bf(acc[s][no][0] * inv);
      o[1] = f2bf(acc[s][no][1] * inv);
      o[2] = f2bf(acc[s][no][2] * inv);
      o[3] = f2bf(acc[s][no][3] * inv);
      *reinterpret_cast<v4u*>(
          &ctx[(size_t)(b * S + qrow + s * 16) * 1024 + hh * 64 + no * 16 + g * 4]) = o;
    }
  }
}

// ------------------------------------------------------------------
extern "C" void kernel_launch(void* const* d_in, const int* in_sizes, int n_in,
                              void* d_out, int out_size, void* d_ws, size_t ws_size,
                              hipStream_t stream)
{
  (void)in_sizes; (void)n_in; (void)out_size; (void)ws_size;
  const float* x    = (const float*)d_in[0];
  const int*   mask = (const int*)d_in[1];
  const float* Wq = (const float*)d_in[2];  const float* bq = (const float*)d_in[3];
  const float* Wk = (const float*)d_in[4];  const float* bk = (const float*)d_in[5];
  const float* Wv = (const float*)d_in[6];  const float* bv = (const float*)d_in[7];
  const float* Wo = (const float*)d_in[8];  const float* bo = (const float*)d_in[9];
  const float* W1 = (const float*)d_in[10]; const float* b1 = (const float*)d_in[11];
  const float* W2 = (const float*)d_in[12]; const float* b2 = (const float*)d_in[13];
  const float* ln1a = (const float*)d_in[14]; const float* ln1b = (const float*)d_in[15];
  const float* ln2a = (const float*)d_in[16]; const float* ln2b = (const float*)d_in[17];

  char* ws = (char*)d_ws;
  const size_t MB = (size_t)1 << 20;
  unsigned short* wqkvT = (unsigned short*)(ws + 0 * MB);  // [3072][1024]
  unsigned short* woT = (unsigned short*)(ws + 6 * MB);    // [1024][1024]
  unsigned short* w1T = (unsigned short*)(ws + 8 * MB);    // [4096][1024]
  unsigned short* w2T = (unsigned short*)(ws + 16 * MB);   // [1024][4096]
  unsigned short* hb  = (unsigned short*)(ws + 24 * MB);   // LN out, 8192x1024
  unsigned short* qb  = (unsigned short*)(ws + 40 * MB);   // [bh][S][64], pre-scaled
  unsigned short* kb  = (unsigned short*)(ws + 56 * MB);   // [bh][S][64]
  unsigned short* vPb = (unsigned short*)(ws + 72 * MB);   // [bh][32][64][64] permuted
  unsigned short* ctx = (unsigned short*)(ws + 88 * MB);   // 8192x1024
  unsigned short* gb  = (unsigned short*)(ws + 40 * MB);   // FFN mid (aliases dead bufs)
  float* xout = (float*)d_out;

  dim3 tb(32, 8);
  transpose_convert<<<dim3(32, 32),  tb, 0, stream>>>(Wq, wqkvT,               1024, 1024);
  transpose_convert<<<dim3(32, 32),  tb, 0, stream>>>(Wk, wqkvT + 1024 * 1024, 1024, 1024);
  transpose_convert<<<dim3(32, 32),  tb, 0, stream>>>(Wv, wqkvT + 2048 * 1024, 1024, 1024);
  transpose_convert<<<dim3(32, 32),  tb, 0, stream>>>(Wo, woT, 1024, 1024);
  transpose_convert<<<dim3(128, 32), tb, 0, stream>>>(W1, w1T, 1024, 4096);
  transpose_convert<<<dim3(32, 128), tb, 0, stream>>>(W2, w2T, 4096, 1024);

  ln_kernel<<<8192, 256, 0, stream>>>(x, hb, ln1a, ln1b);

  // QKV merged: M=8192, N=3072 -> 32 x 12 = 384 WGs (256^2 tiles)
  gemm_256<MODE_QKV><<<384, 512, 0, stream>>>(
      hb, wqkvT, bq, bk, bv, qb, kb, vPb, 8192, 3072, 1024);

  attn_kernel<<<dim3(64, 16), 256, 0, stream>>>(qb, kb, vPb, mask, ctx);

  // WO: 64 x 4 = 256 WGs
  gemm_pipe_res<<<256, 512, 0, stream>>>(ctx, woT, bo, x, xout, 8192, 1024, 1024);

  ln_kernel<<<8192, 256, 0, stream>>>(xout, hb, ln2a, ln2b);

  // FFN1: 256^2 -> 32 x 16 = 512 WGs
  gemm_256<MODE_FFN1><<<512, 512, 0, stream>>>(
      hb, w1T, b1, nullptr, nullptr, gb, nullptr, nullptr, 8192, 4096, 1024);

  // FFN2: 64 x 4 = 256 WGs
  gemm_pipe_res<<<256, 512, 0, stream>>>(gb, w2T, b2, xout, xout, 8192, 1024, 4096);
}

// Round 11
// 368.431 us; speedup vs baseline: 1.3896x; 1.0895x over previous
//
#include <hip/hip_runtime.h>

typedef __attribute__((ext_vector_type(8))) short v8s;
typedef __attribute__((ext_vector_type(8))) unsigned short v8u;
typedef __attribute__((ext_vector_type(4))) unsigned short v4u;
typedef __attribute__((ext_vector_type(4))) float f32x4;

#define DEV __device__ __forceinline__

DEV unsigned short f2bf(float f) {
  union { float f; unsigned u; } v; v.f = f;
  unsigned r = v.u + 0x7fffu + ((v.u >> 16) & 1u);
  return (unsigned short)(r >> 16);
}

DEV float fexp2(float x) {
  float r; asm("v_exp_f32 %0, %1" : "=v"(r) : "v"(x)); return r;
}

DEV void gload16(const unsigned short* g, unsigned short* l) {
  __builtin_amdgcn_global_load_lds(
      (const __attribute__((address_space(1))) unsigned int*)g,
      (__attribute__((address_space(3))) unsigned int*)l, 16, 0, 0);
}

#define SL2E 0.1803368801111204f  // 0.125 * log2(e)

// ------------------------------------------------------------------
// LayerNorm -> bf16
// ------------------------------------------------------------------
__global__ __launch_bounds__(256) void ln_kernel(
    const float* __restrict__ x, unsigned short* __restrict__ h,
    const float* __restrict__ alpha, const float* __restrict__ beta)
{
  int row = blockIdx.x;
  int tid = threadIdx.x;
  const float4* xr = reinterpret_cast<const float4*>(x + (size_t)row * 1024);
  float4 v = xr[tid];
  float s  = v.x + v.y + v.z + v.w;
  float ss = v.x * v.x + v.y * v.y + v.z * v.z + v.w * v.w;
#pragma unroll
  for (int off = 1; off < 64; off <<= 1) {
    s  += __shfl_xor(s, off);
    ss += __shfl_xor(ss, off);
  }
  __shared__ float ps[4][2];
  int wid = tid >> 6, lane = tid & 63;
  if (lane == 0) { ps[wid][0] = s; ps[wid][1] = ss; }
  __syncthreads();
  s  = ps[0][0] + ps[1][0] + ps[2][0] + ps[3][0];
  ss = ps[0][1] + ps[1][1] + ps[2][1] + ps[3][1];
  float mean = s * (1.0f / 1024.0f);
  float var  = (ss - 1024.0f * mean * mean) * (1.0f / 1023.0f);
  float inv  = 1.0f / (sqrtf(fmaxf(var, 0.0f)) + 1e-6f);
  float a = alpha[0], b = beta[0];
  v4u o;
  o[0] = f2bf(a * ((v.x - mean) * inv) + b);
  o[1] = f2bf(a * ((v.y - mean) * inv) + b);
  o[2] = f2bf(a * ((v.z - mean) * inv) + b);
  o[3] = f2bf(a * ((v.w - mean) * inv) + b);
  *reinterpret_cast<v4u*>(h + (size_t)row * 1024 + tid * 4) = o;
}

// ------------------------------------------------------------------
// fp32 W[K][N] -> bf16 Wt[N][K]
// ------------------------------------------------------------------
__global__ __launch_bounds__(256) void transpose_convert(
    const float* __restrict__ W, unsigned short* __restrict__ Wt, int K, int N)
{
  __shared__ float t[32][33];
  int n0 = blockIdx.x * 32, k0 = blockIdx.y * 32;
  int tx = threadIdx.x, ty = threadIdx.y;
#pragma unroll
  for (int i = 0; i < 4; ++i)
    t[ty + i * 8][tx] = W[(size_t)(k0 + ty + i * 8) * N + n0 + tx];
  __syncthreads();
#pragma unroll
  for (int i = 0; i < 4; ++i)
    Wt[(size_t)(n0 + ty + i * 8) * K + k0 + tx] = f2bf(t[tx][ty + i * 8]);
}

// ------------------------------------------------------------------
// shared staging helper (128x256 tiles)
// ------------------------------------------------------------------
#define BUF_ELEMS ((128 + 256) * 64)

DEV void stage_part(const unsigned short* Aptr, const unsigned short* Bptr,
                    unsigned short* buf, int K, int part, int wid, int lane)
{
  {
    int d = (part * 8 + wid) * 64 + lane;
    int r = d >> 3, p = d & 7;
    gload16(Aptr + (size_t)r * K + 8 * (p ^ (r & 7)),
            buf + (size_t)(part * 8 + wid) * 512);
  }
#pragma unroll
  for (int j = 0; j < 2; ++j) {
    int ib = part * 2 + j;
    int d = (ib * 8 + wid) * 64 + lane;
    int r = d >> 3, p = d & 7;
    gload16(Bptr + (size_t)r * K + 8 * (p ^ (r & 7)),
            buf + 128 * 64 + (size_t)(ib * 8 + wid) * 512);
  }
}

// ------------------------------------------------------------------
// QKV GEMM (128x256, BK=64, ring-3, counted vmcnt(6), one barrier/tile)
// epilogue: Q pre-scaled, K plain, V permuted for attn.
// ------------------------------------------------------------------
__global__ __launch_bounds__(512, 2) void gemm_qkv(
    const unsigned short* __restrict__ A, const unsigned short* __restrict__ Bt,
    const float* __restrict__ bq, const float* __restrict__ bk2,
    const float* __restrict__ bv,
    unsigned short* __restrict__ oq, unsigned short* __restrict__ ok2,
    unsigned short* __restrict__ ov, int M, int N, int K)
{
  __shared__ unsigned short lds[3 * BUF_ELEMS];

  int nbx = M >> 7, nwg = gridDim.x;
  int lin = blockIdx.x;
  int qq = nwg >> 3, rr = nwg & 7;
  int xcd = lin & 7, idx = lin >> 3;
  int swz = (xcd < rr ? xcd * (qq + 1) : rr * (qq + 1) + (xcd - rr) * qq) + idx;
  int bx = swz % nbx, by = swz / nbx;

  int tid = threadIdx.x, lane = tid & 63, wid = tid >> 6;
  int wm = wid >> 2, wn = wid & 3;
  int g = lane >> 4, c0 = lane & 15;
  int rowBase = bx * 128, colBase = by * 256;

  const unsigned short* Ab = A  + (size_t)rowBase * K;
  const unsigned short* Bb = Bt + (size_t)colBase * K;
  int NT = K >> 6;

  f32x4 acc[4][4];
#pragma unroll
  for (int m = 0; m < 4; ++m)
#pragma unroll
    for (int n = 0; n < 4; ++n) acc[m][n] = (f32x4){0.f, 0.f, 0.f, 0.f};

  stage_part(Ab, Bb, lds, K, 0, wid, lane);
  stage_part(Ab, Bb, lds, K, 1, wid, lane);
  stage_part(Ab + 64, Bb + 64, lds + BUF_ELEMS, K, 0, wid, lane);
  stage_part(Ab + 64, Bb + 64, lds + BUF_ELEMS, K, 1, wid, lane);
  asm volatile("s_waitcnt vmcnt(6)" ::: "memory");
  __builtin_amdgcn_s_barrier();
  asm volatile("" ::: "memory");

  int cur = 0;
  for (int t = 0; t < NT; ++t) {
    const char* Abuf = (const char*)(lds + cur * BUF_ELEMS);
    const char* Bbuf = Abuf + 128 * 128;
    int nxt2 = cur + 2; if (nxt2 >= 3) nxt2 -= 3;
    unsigned short* sbuf = lds + nxt2 * BUF_ELEMS;
    bool doStage = (t + 2 < NT);
    int ks_ = (t + 2) << 6;
    int e = (c0 & 7) << 4;

#pragma unroll
    for (int ph = 0; ph < 2; ++ph) {
      v8s af[4], bfr[4];
#pragma unroll
      for (int m = 0; m < 4; ++m)
        af[m] = *reinterpret_cast<const v8s*>(
            Abuf + (wm * 64 + m * 16 + c0) * 128 + ((ph * 64 + g * 16) ^ e));
#pragma unroll
      for (int n = 0; n < 4; ++n)
        bfr[n] = *reinterpret_cast<const v8s*>(
            Bbuf + (wn * 64 + n * 16 + c0) * 128 + ((ph * 64 + g * 16) ^ e));

      if (doStage) stage_part(Ab + ks_, Bb + ks_, sbuf, K, ph, wid, lane);

      __builtin_amdgcn_s_setprio(1);
#pragma unroll
      for (int m = 0; m < 4; ++m)
#pragma unroll
        for (int n = 0; n < 4; ++n)
          acc[m][n] = __builtin_amdgcn_mfma_f32_16x16x32_bf16(
              af[m], bfr[n], acc[m][n], 0, 0, 0);
      __builtin_amdgcn_s_setprio(0);
    }

    if (doStage)            asm volatile("s_waitcnt vmcnt(6)" ::: "memory");
    else if (t + 1 < NT)    asm volatile("s_waitcnt vmcnt(0)" ::: "memory");
    __builtin_amdgcn_sched_barrier(0);
    __builtin_amdgcn_s_barrier();
    asm volatile("" ::: "memory");
    cur = cur + 1; if (cur >= 3) cur -= 3;
  }

#pragma unroll
  for (int mf = 0; mf < 4; ++mf) {
#pragma unroll
    for (int nf = 0; nf < 4; ++nf) {
#pragma unroll
      for (int r = 0; r < 4; ++r) {
        int row = rowBase + wm * 64 + mf * 16 + g * 4 + r;
        int col = colBase + wn * 64 + nf * 16 + c0;
        int sect = colBase >> 10;              // block-uniform
        int cs = col & 1023;
        const float* bp = sect == 0 ? bq : (sect == 1 ? bk2 : bv);
        float v = acc[mf][nf][r] + bp[cs];
        int hh = cs >> 6, d = cs & 63;
        int b = row >> 11, sI = row & 2047;
        size_t bh = (size_t)(b * 16 + hh);
        if (sect == 0) {
          oq[(bh * 2048 + sI) * 64 + d] = f2bf(v * SL2E);
        } else if (sect == 1) {
          ok2[(bh * 2048 + sI) * 64 + d] = f2bf(v);
        } else {
          int k6 = sI & 63;
          int slot = ((k6 >> 5) << 5) | (((k6 >> 2) & 3) << 3) |
                     (((k6 >> 4) & 1) << 2) | (k6 & 3);
          int e2 = slot ^ ((d & 7) << 3);
          ov[((bh * 32 + (sI >> 6)) * 64 + d) * 64 + e2] = f2bf(v);
        }
      }
    }
  }
}

// ------------------------------------------------------------------
// 256x256 FFN1 GEMM (round-9 form: split staging across phases)
// ------------------------------------------------------------------
__global__ __launch_bounds__(512, 1) void gemm_ffn1_256(
    const unsigned short* __restrict__ A, const unsigned short* __restrict__ Bt,
    const float* __restrict__ bias, unsigned short* __restrict__ out,
    int M, int N, int K)
{
  __shared__ unsigned short lds[2][512 * 64];

  int nbx = M >> 8, nwg = gridDim.x;
  int lin = blockIdx.x;
  int qq = nwg >> 3, rr = nwg & 7;
  int xcd = lin & 7, idx = lin >> 3;
  int swz = (xcd < rr ? xcd * (qq + 1) : rr * (qq + 1) + (xcd - rr) * qq) + idx;
  int bx = swz % nbx, by = swz / nbx;

  int tid = threadIdx.x, lane = tid & 63, wid = tid >> 6;
  int wm = wid >> 2, wn = wid & 3;
  int g = lane >> 4, c0 = lane & 15;
  int rowBase = bx * 256, colBase = by * 256;

  const unsigned short* Ab = A  + (size_t)rowBase * K;
  const unsigned short* Bb = Bt + (size_t)colBase * K;
  int NT = K >> 6;

  const unsigned short* src[8]; int dq[8];
#pragma unroll
  for (int i = 0; i < 8; ++i) {
    int q = i * 512 + tid;
    dq[i] = q;
    if (i < 4) {
      int r = q >> 3, p = q & 7;
      src[i] = Ab + (size_t)r * K + 8 * (p ^ (r & 7));
    } else {
      int qb2 = q - 2048, r = qb2 >> 3, p = qb2 & 7;
      src[i] = Bb + (size_t)r * K + 8 * (p ^ (r & 7));
    }
  }

  f32x4 acc[8][4];
#pragma unroll
  for (int m = 0; m < 8; ++m)
#pragma unroll
    for (int n = 0; n < 4; ++n) acc[m][n] = (f32x4){0.f, 0.f, 0.f, 0.f};

#define STG256(tt, lo, hi) do { \
    unsigned short* sb_ = &lds[(tt) & 1][0]; int ko_ = (tt) << 6; \
    _Pragma("unroll") for (int i = lo; i < hi; ++i) gload16(src[i] + ko_, sb_ + dq[i] * 8); \
  } while (0)

  STG256(0, 0, 8);
  asm volatile("s_waitcnt vmcnt(0)" ::: "memory");
  __builtin_amdgcn_s_barrier();
  asm volatile("" ::: "memory");

  for (int t = 0; t < NT; ++t) {
    const char* buf = (const char*)&lds[t & 1][0];
    bool more = (t + 1 < NT);
    int e = (c0 & 7) << 4;

#pragma unroll
    for (int ph = 0; ph < 2; ++ph) {
      v8s af[8], bfr[4];
#pragma unroll
      for (int m = 0; m < 8; ++m) {
        int row = wm * 128 + m * 16 + c0;
        af[m] = *reinterpret_cast<const v8s*>(
            buf + row * 128 + ((ph * 64 + g * 16) ^ ((row & 7) << 4)));
      }
#pragma unroll
      for (int n = 0; n < 4; ++n) {
        int row = wn * 64 + n * 16 + c0;
        bfr[n] = *reinterpret_cast<const v8s*>(
            buf + 32768 + row * 128 + ((ph * 64 + g * 16) ^ ((row & 7) << 4)));
      }

      if (more) { if (ph == 0) STG256(t + 1, 0, 4); else STG256(t + 1, 4, 8); }

      __builtin_amdgcn_s_setprio(1);
#pragma unroll
      for (int m = 0; m < 8; ++m)
#pragma unroll
        for (int n = 0; n < 4; ++n)
          acc[m][n] = __builtin_amdgcn_mfma_f32_16x16x32_bf16(
              af[m], bfr[n], acc[m][n], 0, 0, 0);
      __builtin_amdgcn_s_setprio(0);
    }

    if (more) asm volatile("s_waitcnt vmcnt(0)" ::: "memory");
    __builtin_amdgcn_sched_barrier(0);
    __builtin_amdgcn_s_barrier();
    asm volatile("" ::: "memory");
  }
#undef STG256

#pragma unroll
  for (int mf = 0; mf < 8; ++mf) {
#pragma unroll
    for (int nf = 0; nf < 4; ++nf) {
#pragma unroll
      for (int r = 0; r < 4; ++r) {
        int row = rowBase + wm * 128 + mf * 16 + g * 4 + r;
        int col = colBase + wn * 64 + nf * 16 + c0;
        float v = acc[mf][nf][r] + bias[col];
        out[(size_t)row * N + col] = f2bf(fmaxf(v, 0.0f));
      }
    }
  }
}

// ------------------------------------------------------------------
// 128x256 GEMM + residual epilogue (WO / FFN2)
// ------------------------------------------------------------------
__global__ __launch_bounds__(512, 2) void gemm_pipe_res(
    const unsigned short* __restrict__ A, const unsigned short* __restrict__ Bt,
    const float* __restrict__ bias0, const float* __restrict__ resid,
    float* __restrict__ o0, int M, int N, int K)
{
  __shared__ unsigned short lds[3 * BUF_ELEMS];

  int nbx = M >> 7, nwg = gridDim.x;
  int lin = blockIdx.x;
  int qq = nwg >> 3, rr = nwg & 7;
  int xcd = lin & 7, idx = lin >> 3;
  int swz = (xcd < rr ? xcd * (qq + 1) : rr * (qq + 1) + (xcd - rr) * qq) + idx;
  int bx = swz % nbx, by = swz / nbx;

  int tid = threadIdx.x, lane = tid & 63, wid = tid >> 6;
  int wm = wid >> 2, wn = wid & 3;
  int g = lane >> 4, c0 = lane & 15;
  int rowBase = bx * 128, colBase = by * 256;

  const unsigned short* Ab = A  + (size_t)rowBase * K;
  const unsigned short* Bb = Bt + (size_t)colBase * K;
  int NT = K >> 6;

  f32x4 acc[4][4];
#pragma unroll
  for (int m = 0; m < 4; ++m)
#pragma unroll
    for (int n = 0; n < 4; ++n) acc[m][n] = (f32x4){0.f, 0.f, 0.f, 0.f};

  stage_part(Ab, Bb, lds, K, 0, wid, lane);
  stage_part(Ab, Bb, lds, K, 1, wid, lane);
  stage_part(Ab + 64, Bb + 64, lds + BUF_ELEMS, K, 0, wid, lane);
  stage_part(Ab + 64, Bb + 64, lds + BUF_ELEMS, K, 1, wid, lane);
  asm volatile("s_waitcnt vmcnt(6)" ::: "memory");
  __builtin_amdgcn_s_barrier();
  asm volatile("" ::: "memory");

  int cur = 0;
  for (int t = 0; t < NT; ++t) {
    const char* Abuf = (const char*)(lds + cur * BUF_ELEMS);
    const char* Bbuf = Abuf + 128 * 128;
    int nxt2 = cur + 2; if (nxt2 >= 3) nxt2 -= 3;
    unsigned short* sbuf = lds + nxt2 * BUF_ELEMS;
    bool doStage = (t + 2 < NT);
    int ks_ = (t + 2) << 6;
    int e = (c0 & 7) << 4;

#pragma unroll
    for (int ph = 0; ph < 2; ++ph) {
      v8s af[4], bfr[4];
#pragma unroll
      for (int m = 0; m < 4; ++m)
        af[m] = *reinterpret_cast<const v8s*>(
            Abuf + (wm * 64 + m * 16 + c0) * 128 + ((ph * 64 + g * 16) ^ e));
#pragma unroll
      for (int n = 0; n < 4; ++n)
        bfr[n] = *reinterpret_cast<const v8s*>(
            Bbuf + (wn * 64 + n * 16 + c0) * 128 + ((ph * 64 + g * 16) ^ e));

      if (doStage) stage_part(Ab + ks_, Bb + ks_, sbuf, K, ph, wid, lane);

      __builtin_amdgcn_s_setprio(1);
#pragma unroll
      for (int m = 0; m < 4; ++m)
#pragma unroll
        for (int n = 0; n < 4; ++n)
          acc[m][n] = __builtin_amdgcn_mfma_f32_16x16x32_bf16(
              af[m], bfr[n], acc[m][n], 0, 0, 0);
      __builtin_amdgcn_s_setprio(0);
    }

    if (doStage)            asm volatile("s_waitcnt vmcnt(6)" ::: "memory");
    else if (t + 1 < NT)    asm volatile("s_waitcnt vmcnt(0)" ::: "memory");
    __builtin_amdgcn_sched_barrier(0);
    __builtin_amdgcn_s_barrier();
    asm volatile("" ::: "memory");
    cur = cur + 1; if (cur >= 3) cur -= 3;
  }

#pragma unroll
  for (int mf = 0; mf < 4; ++mf) {
#pragma unroll
    for (int nf = 0; nf < 4; ++nf) {
#pragma unroll
      for (int r = 0; r < 4; ++r) {
        int row = rowBase + wm * 64 + mf * 16 + g * 4 + r;
        int col = colBase + wn * 64 + nf * 16 + c0;
        float v = acc[mf][nf][r] + bias0[col];
        o0[(size_t)row * N + col] = resid[(size_t)row * N + col] + v;
      }
    }
  }
}

// ------------------------------------------------------------------
// Flash attention v9: QBLK=256 (4 q-sets/wave), ring-3 K/V, counted
// vmcnt(4), raw v_exp, l-sum via ones-MFMA, setprio around PV.
// ------------------------------------------------------------------
__global__ __launch_bounds__(256, 2) void attn_kernel(
    const unsigned short* __restrict__ q, const unsigned short* __restrict__ k,
    const unsigned short* __restrict__ vP, const int* __restrict__ mask,
    unsigned short* __restrict__ ctx)
{
  const int S = 2048, DK = 64, NT = 32;
  int bh = blockIdx.x;
  int b = bh >> 4, hh = bh & 15;
  int qbase = blockIdx.y * 256;
  int tid = threadIdx.x, lane = tid & 63, wid = tid >> 6;
  int g = lane >> 4, c0 = lane & 15;

  __shared__ unsigned short Ks[3 * 4096];
  __shared__ unsigned short Vs[3 * 4096];
  __shared__ unsigned short Mb[2048];

  const unsigned short* qb  = q  + (size_t)bh * S * DK;
  const unsigned short* kb  = k  + (size_t)bh * S * DK;
  const unsigned short* vPb = vP + (size_t)bh * 32 * 4096;
  const int* mb = mask + b * S;

  // ---- mask bias -> LDS (bf16), block-wide all-valid flag ----
  const int4* mb4 = reinterpret_cast<const int4*>(mb);
  int4 ma = mb4[tid * 2], mc = mb4[tid * 2 + 1];
  unsigned short bneg = f2bf(-1e9f);
  v8u bw;
  bw[0] = ma.x ? 0 : bneg; bw[1] = ma.y ? 0 : bneg;
  bw[2] = ma.z ? 0 : bneg; bw[3] = ma.w ? 0 : bneg;
  bw[4] = mc.x ? 0 : bneg; bw[5] = mc.y ? 0 : bneg;
  bw[6] = mc.z ? 0 : bneg; bw[7] = mc.w ? 0 : bneg;
  *reinterpret_cast<v8u*>(&Mb[tid * 8]) = bw;
  int okm = (ma.x && ma.y && ma.z && ma.w && mc.x && mc.y && mc.z && mc.w) ? 1 : 0;
  int allValid = __syncthreads_and(okm);

  // ---- Q fragments: 4 sets of 16 rows ----
  int qrow = qbase + wid * 64 + c0;
  v8s aq[4][2];
#pragma unroll
  for (int s = 0; s < 4; ++s)
#pragma unroll
    for (int t = 0; t < 2; ++t)
      aq[s][t] = *reinterpret_cast<const v8s*>(
          &qb[(size_t)(qrow + s * 16) * DK + t * 32 + g * 8]);

  int i0 = tid, i1 = tid + 256;
  int r0 = i0 >> 3, m0 = i0 & 7;
  int r1 = i1 >> 3, m1 = i1 & 7;
  int ko0 = r0 * DK + 8 * (m0 ^ (r0 & 7));
  int ko1 = r1 * DK + 8 * (m1 ^ (r1 & 7));

  f32x4 acc[4][4], accl[4];
#pragma unroll
  for (int s = 0; s < 4; ++s) {
    accl[s] = (f32x4){0.f, 0.f, 0.f, 0.f};
#pragma unroll
    for (int no = 0; no < 4; ++no) acc[s][no] = (f32x4){0.f, 0.f, 0.f, 0.f};
  }
  v8s ones;
#pragma unroll
  for (int j = 0; j < 8; ++j) ones[j] = (short)0x3F80;  // bf16 1.0

#define ASTAGE(bi, tt) do { \
    int tb_ = (tt) * 4096; \
    gload16(kb + tb_ + ko0, Ks + (bi) * 4096 + i0 * 8); \
    gload16(kb + tb_ + ko1, Ks + (bi) * 4096 + i1 * 8); \
    gload16(vPb + tb_ + i0 * 8, Vs + (bi) * 4096 + i0 * 8); \
    gload16(vPb + tb_ + i1 * 8, Vs + (bi) * 4096 + i1 * 8); \
  } while (0)

  ASTAGE(0, 0);
  ASTAGE(1, 1);
  asm volatile("s_waitcnt vmcnt(4)" ::: "memory");
  __builtin_amdgcn_s_barrier();
  asm volatile("" ::: "memory");

  int cur = 0, nx2 = 2;
  for (int t = 0; t < NT; ++t) {
    bool more2 = (t + 2 < NT);
    if (more2) ASTAGE(nx2, t + 2);
    const unsigned short* Kc = Ks + cur * 4096;
    const unsigned short* Vc = Vs + cur * 4096;

    v8s pb[4][2];
#pragma unroll
    for (int pp = 0; pp < 2; ++pp) {
      float pA[16], pB[16];
#pragma unroll
      for (int n = 0; n < 4; ++n) {
        int kvr = n * 16 + c0;
        const char* krow = (const char*)(Kc + kvr * DK);
        int sw = (kvr & 7) << 4;
        v8s ak0 = *reinterpret_cast<const v8s*>(krow + ((g * 16) ^ sw));
        v8s ak1 = *reinterpret_cast<const v8s*>(krow + ((64 + g * 16) ^ sw));
        f32x4 s0 = (f32x4){0.f, 0.f, 0.f, 0.f};
        f32x4 s1 = (f32x4){0.f, 0.f, 0.f, 0.f};
        s0 = __builtin_amdgcn_mfma_f32_16x16x32_bf16(ak0, aq[pp * 2][0], s0, 0, 0, 0);
        s0 = __builtin_amdgcn_mfma_f32_16x16x32_bf16(ak1, aq[pp * 2][1], s0, 0, 0, 0);
        s1 = __builtin_amdgcn_mfma_f32_16x16x32_bf16(ak0, aq[pp * 2 + 1][0], s1, 0, 0, 0);
        s1 = __builtin_amdgcn_mfma_f32_16x16x32_bf16(ak1, aq[pp * 2 + 1][1], s1, 0, 0, 0);
#pragma unroll
        for (int r = 0; r < 4; ++r) { pA[n * 4 + r] = s0[r]; pB[n * 4 + r] = s1[r]; }
      }
      if (!allValid) {
#pragma unroll
        for (int n = 0; n < 4; ++n) {
          v4u mbv = *reinterpret_cast<const v4u*>(&Mb[t * 64 + n * 16 + g * 4]);
#pragma unroll
          for (int r = 0; r < 4; ++r) {
            union { unsigned u; float f; } cv; cv.u = ((unsigned)mbv[r]) << 16;
            pA[n * 4 + r] += cv.f; pB[n * 4 + r] += cv.f;
          }
        }
      }
#pragma unroll
      for (int i = 0; i < 16; ++i) { pA[i] = fexp2(pA[i]); pB[i] = fexp2(pB[i]); }
#pragma unroll
      for (int c = 0; c < 2; ++c) {
        union { v8s s; unsigned u[4]; } kA, kB;
#pragma unroll
        for (int hp = 0; hp < 4; ++hp) {
          asm("v_cvt_pk_bf16_f32 %0, %1, %2"
              : "=v"(kA.u[hp]) : "v"(pA[c * 8 + 2 * hp]), "v"(pA[c * 8 + 2 * hp + 1]));
          asm("v_cvt_pk_bf16_f32 %0, %1, %2"
              : "=v"(kB.u[hp]) : "v"(pB[c * 8 + 2 * hp]), "v"(pB[c * 8 + 2 * hp + 1]));
        }
        pb[pp * 2][c] = kA.s; pb[pp * 2 + 1][c] = kB.s;
      }
    }

    // ---- PV + l (ones-row), V frags read once for all 4 sets ----
    __builtin_amdgcn_s_setprio(1);
#pragma unroll
    for (int c = 0; c < 2; ++c) {
#pragma unroll
      for (int no = 0; no < 4; ++no) {
        int d = no * 16 + c0;
        v8s av = *reinterpret_cast<const v8s*>(
            (const char*)(Vc + d * 64) + ((c * 64 + g * 16) ^ ((d & 7) << 4)));
#pragma unroll
        for (int s = 0; s < 4; ++s)
          acc[s][no] = __builtin_amdgcn_mfma_f32_16x16x32_bf16(av, pb[s][c], acc[s][no], 0, 0, 0);
      }
#pragma unroll
      for (int s = 0; s < 4; ++s)
        accl[s] = __builtin_amdgcn_mfma_f32_16x16x32_bf16(ones, pb[s][c], accl[s], 0, 0, 0);
    }
    __builtin_amdgcn_s_setprio(0);

    if (more2)              asm volatile("s_waitcnt vmcnt(4)" ::: "memory");
    else if (t + 1 < NT)    asm volatile("s_waitcnt vmcnt(0)" ::: "memory");
    __builtin_amdgcn_sched_barrier(0);
    __builtin_amdgcn_s_barrier();
    asm volatile("" ::: "memory");
    cur = (cur + 1 < 3) ? cur + 1 : 0;
    nx2 = (nx2 + 1 < 3) ? nx2 + 1 : 0;
  }
#undef ASTAGE

#pragma unroll
  for (int s = 0; s < 4; ++s) {
    float inv = 1.0f / fmaxf(accl[s][0], 1e-30f);
#pragma unroll
    for (int no = 0; no < 4; ++no) {
      v4u o;
      o[0] = f2bf(acc[s][no][0] * inv);
      o[1] = f2bf(acc[s][no][1] * inv);
      o[2] = f2bf(acc[s][no][2] * inv);
      o[3] = f2bf(acc[s][no][3] * inv);
      *reinterpret_cast<v4u*>(
          &ctx[(size_t)(b * S + qrow + s * 16) * 1024 + hh * 64 + no * 16 + g * 4]) = o;
    }
  }
}

// ------------------------------------------------------------------
extern "C" void kernel_launch(void* const* d_in, const int* in_sizes, int n_in,
                              void* d_out, int out_size, void* d_ws, size_t ws_size,
                              hipStream_t stream)
{
  (void)in_sizes; (void)n_in; (void)out_size; (void)ws_size;
  const float* x    = (const float*)d_in[0];
  const int*   mask = (const int*)d_in[1];
  const float* Wq = (const float*)d_in[2];  const float* bq = (const float*)d_in[3];
  const float* Wk = (const float*)d_in[4];  const float* bk = (const float*)d_in[5];
  const float* Wv = (const float*)d_in[6];  const float* bv = (const float*)d_in[7];
  const float* Wo = (const float*)d_in[8];  const float* bo = (const float*)d_in[9];
  const float* W1 = (const float*)d_in[10]; const float* b1 = (const float*)d_in[11];
  const float* W2 = (const float*)d_in[12]; const float* b2 = (const float*)d_in[13];
  const float* ln1a = (const float*)d_in[14]; const float* ln1b = (const float*)d_in[15];
  const float* ln2a = (const float*)d_in[16]; const float* ln2b = (const float*)d_in[17];

  char* ws = (char*)d_ws;
  const size_t MB = (size_t)1 << 20;
  unsigned short* wqkvT = (unsigned short*)(ws + 0 * MB);  // [3072][1024]
  unsigned short* woT = (unsigned short*)(ws + 6 * MB);    // [1024][1024]
  unsigned short* w1T = (unsigned short*)(ws + 8 * MB);    // [4096][1024]
  unsigned short* w2T = (unsigned short*)(ws + 16 * MB);   // [1024][4096]
  unsigned short* hb  = (unsigned short*)(ws + 24 * MB);   // LN out, 8192x1024
  unsigned short* qb  = (unsigned short*)(ws + 40 * MB);   // [bh][S][64], pre-scaled
  unsigned short* kb  = (unsigned short*)(ws + 56 * MB);   // [bh][S][64]
  unsigned short* vPb = (unsigned short*)(ws + 72 * MB);   // [bh][32][64][64] permuted
  unsigned short* ctx = (unsigned short*)(ws + 88 * MB);   // 8192x1024
  unsigned short* gb  = (unsigned short*)(ws + 40 * MB);   // FFN mid (aliases dead bufs)
  float* xout = (float*)d_out;

  dim3 tb(32, 8);
  transpose_convert<<<dim3(32, 32),  tb, 0, stream>>>(Wq, wqkvT,               1024, 1024);
  transpose_convert<<<dim3(32, 32),  tb, 0, stream>>>(Wk, wqkvT + 1024 * 1024, 1024, 1024);
  transpose_convert<<<dim3(32, 32),  tb, 0, stream>>>(Wv, wqkvT + 2048 * 1024, 1024, 1024);
  transpose_convert<<<dim3(32, 32),  tb, 0, stream>>>(Wo, woT, 1024, 1024);
  transpose_convert<<<dim3(128, 32), tb, 0, stream>>>(W1, w1T, 1024, 4096);
  transpose_convert<<<dim3(32, 128), tb, 0, stream>>>(W2, w2T, 4096, 1024);

  ln_kernel<<<8192, 256, 0, stream>>>(x, hb, ln1a, ln1b);

  // QKV merged: M=8192, N=3072 -> 64 x 12 = 768 WGs (128x256 tiles)
  gemm_qkv<<<768, 512, 0, stream>>>(hb, wqkvT, bq, bk, bv, qb, kb, vPb, 8192, 3072, 1024);

  attn_kernel<<<dim3(64, 8), 256, 0, stream>>>(qb, kb, vPb, mask, ctx);

  // WO: 64 x 4 = 256 WGs
  gemm_pipe_res<<<256, 512, 0, stream>>>(ctx, woT, bo, x, xout, 8192, 1024, 1024);

  ln_kernel<<<8192, 256, 0, stream>>>(xout, hb, ln2a, ln2b);

  // FFN1: 256^2 -> 32 x 16 = 512 WGs
  gemm_ffn1_256<<<512, 512, 0, stream>>>(hb, w1T, b1, gb, 8192, 4096, 1024);

  // FFN2: 64 x 4 = 256 WGs
  gemm_pipe_res<<<256, 512, 0, stream>>>(gb, w2T, b2, xout, xout, 8192, 1024, 4096);
}